// Round 2
// baseline (2977.630 us; speedup 1.0000x reference)
//
#include <hip/hip_runtime.h>
#include <cstdint>
#include <cstddef>

#define PP 2048
#define KK 10
#define LL 3
#define EE 256
#define HH 512
#define NPK (PP*KK)      // 20480
#define FOURH (4*HH)     // 2048
#define CH_PAIRS 256
#define CH_ROWS (CH_PAIRS*KK)   // 2560
#define N_CHUNK (PP/CH_PAIRS)   // 8

__device__ __forceinline__ float sigf(float x) { return 1.0f / (1.0f + expf(-x)); }

#define ACC4(d, s) do { d.x += (s).x; d.y += (s).y; d.z += (s).z; d.w += (s).w; } while (0)

// ---------------- tiled transpose: dst[C][R] = src[R][C] ----------------
__global__ __launch_bounds__(256) void transpose_k(const float* __restrict__ src,
                                                   float* __restrict__ dst, int R, int C) {
    __shared__ float t[32][33];
    int bx = blockIdx.x * 32, by = blockIdx.y * 32;
    int x = threadIdx.x & 31, y = threadIdx.x >> 5;
    for (int i = y; i < 32; i += 8) {
        int r = by + i, c = bx + x;
        if (r < R && c < C) t[i][x] = src[(size_t)r * C + c];
    }
    __syncthreads();
    for (int i = y; i < 32; i += 8) {
        int c = bx + i, r = by + x;
        if (r < R && c < C) dst[(size_t)c * R + r] = t[x][i];
    }
}

// ------------- out[j] = dot(A[j, :Kd], vec) + add1[j] + add2[j] -------------
__global__ __launch_bounds__(256) void rowdot(const float* __restrict__ A, int lda,
                                              const float* __restrict__ vec, int Kd,
                                              const float* __restrict__ add1,
                                              const float* __restrict__ add2,
                                              float* __restrict__ out, int M) {
    int w = threadIdx.x >> 6, lane = threadIdx.x & 63;
    int row = blockIdx.x * 4 + w;
    if (row >= M) return;
    float acc = 0.f;
    for (int k = lane; k < Kd; k += 64) acc += A[(size_t)row * lda + k] * vec[k];
    for (int off = 32; off; off >>= 1) acc += __shfl_down(acc, off, 64);
    if (lane == 0) {
        float r = acc;
        if (add1) r += add1[row];
        if (add2) r += add2[row];
        out[row] = r;
    }
}

// ---------------- C[M,N] = A[M,K] @ B[N,K]^T (+ bias[N]) ----------------
// 128x64 tile, 256 threads, fp32 VALU. N multiple of 64, K multiple of 16 (true here).
__global__ __launch_bounds__(256) void gemm_abt(
    const float* __restrict__ A, int lda,
    const float* __restrict__ B, int ldb,
    float* __restrict__ C, int ldc,
    int M, int N, int K, const float* __restrict__ bias)
{
    __shared__ float As[16][128];
    __shared__ float Bs[16][64];
    int tid = threadIdx.x;
    int col0 = blockIdx.x * 64;
    int row0 = blockIdx.y * 128;
    int tx = tid & 15, ty = tid >> 4;
    float acc[8][4];
#pragma unroll
    for (int i = 0; i < 8; ++i)
#pragma unroll
        for (int j = 0; j < 4; ++j) acc[i][j] = 0.f;

    int ak4 = tid & 3;
    int arow0 = tid >> 2; // 0..63
    for (int kt = 0; kt < K; kt += 16) {
#pragma unroll
        for (int i = 0; i < 2; ++i) {
            int row = arow0 + i * 64;
            int gr = row0 + row;
            float4 v = make_float4(0.f, 0.f, 0.f, 0.f);
            if (gr < M) v = *reinterpret_cast<const float4*>(A + (size_t)gr * lda + kt + ak4 * 4);
            As[ak4 * 4 + 0][row] = v.x;
            As[ak4 * 4 + 1][row] = v.y;
            As[ak4 * 4 + 2][row] = v.z;
            As[ak4 * 4 + 3][row] = v.w;
        }
        {
            int row = arow0;
            int gc = col0 + row;
            float4 v = make_float4(0.f, 0.f, 0.f, 0.f);
            if (gc < N) v = *reinterpret_cast<const float4*>(B + (size_t)gc * ldb + kt + ak4 * 4);
            Bs[ak4 * 4 + 0][row] = v.x;
            Bs[ak4 * 4 + 1][row] = v.y;
            Bs[ak4 * 4 + 2][row] = v.z;
            Bs[ak4 * 4 + 3][row] = v.w;
        }
        __syncthreads();
#pragma unroll
        for (int kk = 0; kk < 16; ++kk) {
            float4 a0 = *reinterpret_cast<const float4*>(&As[kk][ty * 8]);
            float4 a1 = *reinterpret_cast<const float4*>(&As[kk][ty * 8 + 4]);
            float4 b  = *reinterpret_cast<const float4*>(&Bs[kk][tx * 4]);
            float av[8] = {a0.x, a0.y, a0.z, a0.w, a1.x, a1.y, a1.z, a1.w};
            float bv[4] = {b.x, b.y, b.z, b.w};
#pragma unroll
            for (int i = 0; i < 8; ++i)
#pragma unroll
                for (int j = 0; j < 4; ++j)
                    acc[i][j] += av[i] * bv[j];
        }
        __syncthreads();
    }
    float bb[4] = {0.f, 0.f, 0.f, 0.f};
    if (bias) {
        bb[0] = bias[col0 + tx * 4 + 0];
        bb[1] = bias[col0 + tx * 4 + 1];
        bb[2] = bias[col0 + tx * 4 + 2];
        bb[3] = bias[col0 + tx * 4 + 3];
    }
#pragma unroll
    for (int i = 0; i < 8; ++i) {
        int gr = row0 + ty * 8 + i;
        if (gr < M) {
            float4 o;
            o.x = acc[i][0] + bb[0];
            o.y = acc[i][1] + bb[1];
            o.z = acc[i][2] + bb[2];
            o.w = acc[i][3] + bb[3];
            *reinterpret_cast<float4*>(C + (size_t)gr * ldc + col0 + tx * 4) = o;
        }
    }
}

// ---------------- LSTM pointwise: gates from gathered tables (+ G) ----------------
// h/c/pemb are CHUNK-LOCAL (nrows rows); idx/lens are global via row0.
__global__ __launch_bounds__(256) void lstm_update(
    const float* __restrict__ G,
    const float* __restrict__ relg, const float* __restrict__ entg,
    const int* __restrict__ rel_idx, const int* __restrict__ ent_idx,
    const int* __restrict__ lens_,
    float* __restrict__ hbuf, float* __restrict__ cbuf, float* __restrict__ pemb,
    int t, int row0, int nrows)
{
    int gid = blockIdx.x * 256 + threadIdx.x;
    if (gid >= nrows * 128) return;
    int nl = gid >> 7, j4 = gid & 127;
    int n = row0 + nl;
    int r = rel_idx[n * 3 + t];
    int e = ent_idx[n * 3 + t];
    const float4* rg = reinterpret_cast<const float4*>(relg + (size_t)r * FOURH);
    const float4* eg = reinterpret_cast<const float4*>(entg + (size_t)e * FOURH);
    float4 gi = rg[j4], gf = rg[j4 + 128], gg = rg[j4 + 256], go = rg[j4 + 384];
    float4 e0 = eg[j4], e1 = eg[j4 + 128], e2 = eg[j4 + 256], e3 = eg[j4 + 384];
    ACC4(gi, e0); ACC4(gf, e1); ACC4(gg, e2); ACC4(go, e3);
    if (G) {
        const float4* gp = reinterpret_cast<const float4*>(G + (size_t)nl * FOURH);
        float4 a0 = gp[j4], a1 = gp[j4 + 128], a2 = gp[j4 + 256], a3 = gp[j4 + 384];
        ACC4(gi, a0); ACC4(gf, a1); ACC4(gg, a2); ACC4(go, a3);
    }
    float4 cold = make_float4(0.f, 0.f, 0.f, 0.f);
    if (t > 0) cold = reinterpret_cast<const float4*>(cbuf)[(size_t)nl * 128 + j4];
    float4 cn, hn;
    cn.x = sigf(gf.x) * cold.x + sigf(gi.x) * tanhf(gg.x); hn.x = sigf(go.x) * tanhf(cn.x);
    cn.y = sigf(gf.y) * cold.y + sigf(gi.y) * tanhf(gg.y); hn.y = sigf(go.y) * tanhf(cn.y);
    cn.z = sigf(gf.z) * cold.z + sigf(gi.z) * tanhf(gg.z); hn.z = sigf(go.z) * tanhf(cn.z);
    cn.w = sigf(gf.w) * cold.w + sigf(gi.w) * tanhf(gg.w); hn.w = sigf(go.w) * tanhf(cn.w);
    reinterpret_cast<float4*>(cbuf)[(size_t)nl * 128 + j4] = cn;
    reinterpret_cast<float4*>(hbuf)[(size_t)nl * 128 + j4] = hn;
    int len = lens_[n];
    int last = len - 1;
    if (last < 0) last = 0;
    if (last > 2) last = 2;
    if (last == t) {
        float4 pv = (len > 0) ? hn : make_float4(0.f, 0.f, 0.f, 0.f);
        reinterpret_cast<float4*>(pemb)[(size_t)nl * 128 + j4] = pv;
    }
}

// ---------------- per-pair attention -> mean-over-q context ----------------
// mctx[p, h*128+d] = sum_k ( mean_q softmax_k(q.k/sqrt(Dh)) ) * v[k,h,d]
__global__ __launch_bounds__(256) void attn_kernel(const float* __restrict__ qkv,
                                                   float* __restrict__ mctx, int pair0)
{
    __shared__ float qk[10][1024];   // q (0:512) and k (512:1024) per path
    __shared__ float sc[4][10][10];
    __shared__ float wb[4][10];
    int tid = threadIdx.x;
    const float* base = qkv + (size_t)blockIdx.x * 10 * 1536;
    for (int i = tid; i < 2560; i += 256) {
        int row = i >> 8, c4 = i & 255;
        reinterpret_cast<float4*>(&qk[row][0])[c4] =
            reinterpret_cast<const float4*>(base + (size_t)row * 1536)[c4];
    }
    __syncthreads();
    const float scale = 0.08838834764831845f; // 1/sqrt(128)
    for (int idx = tid; idx < 400; idx += 256) {
        int h = idx / 100, rem = idx % 100, qi = rem / 10, ki = rem % 10;
        const float* qp = &qk[qi][h * 128];
        const float* kp = &qk[ki][512 + h * 128];
        float a = 0.f;
        for (int d = 0; d < 128; ++d) a += qp[d] * kp[d];
        sc[h][qi][ki] = a * scale;
    }
    __syncthreads();
    if (tid < 40) {
        int h = tid / 10, qi = tid % 10;
        float m = -1e30f;
        for (int ki = 0; ki < 10; ++ki) m = fmaxf(m, sc[h][qi][ki]);
        float ex[10]; float s = 0.f;
        for (int ki = 0; ki < 10; ++ki) { ex[ki] = expf(sc[h][qi][ki] - m); s += ex[ki]; }
        float inv = 1.f / s;
        for (int ki = 0; ki < 10; ++ki) sc[h][qi][ki] = ex[ki] * inv;
    }
    __syncthreads();
    if (tid < 40) {
        int h = tid / 10, ki = tid % 10;
        float s = 0.f;
        for (int qi = 0; qi < 10; ++qi) s += sc[h][qi][ki];
        wb[h][ki] = s * 0.1f;
    }
    __syncthreads();
    for (int e = tid; e < 512; e += 256) {
        int h = e >> 7, d = e & 127;
        float a = 0.f;
        for (int ki = 0; ki < 10; ++ki)
            a += wb[h][ki] * base[(size_t)ki * 1536 + 1024 + h * 128 + d];
        mctx[(size_t)(pair0 + blockIdx.x) * 512 + e] = a;
    }
}

extern "C" void kernel_launch(void* const* d_in, const int* in_sizes, int n_in,
                              void* d_out, int out_size, void* d_ws, size_t ws_size,
                              hipStream_t stream)
{
    const int* rel_idx     = (const int*)d_in[0];
    const int* ent_idx     = (const int*)d_in[1];
    const int* path_lens   = (const int*)d_in[2];
    const float* rel_table = (const float*)d_in[3];
    const float* ent_table = (const float*)d_in[4];
    const float* kg_proj_w = (const float*)d_in[5];
    const float* kg_proj_b = (const float*)d_in[6];
    const float* w_ih      = (const float*)d_in[7];
    const float* w_hh      = (const float*)d_in[8];
    const float* b_ih      = (const float*)d_in[9];
    const float* b_hh      = (const float*)d_in[10];
    const float* attn_in_w = (const float*)d_in[11];
    const float* attn_in_b = (const float*)d_in[12];
    const float* attn_out_w = (const float*)d_in[13];
    const float* attn_out_b = (const float*)d_in[14];
    const float* path_proj_w = (const float*)d_in[15];
    const float* path_proj_b = (const float*)d_in[16];
    float* out = (float*)d_out;
    (void)in_sizes; (void)n_in; (void)out_size; (void)ws_size;

    float* ws = (float*)d_ws;
    size_t off = 0;
    auto alloc = [&](size_t n) { float* p = ws + off; off += (n + 63) & ~(size_t)63; return p; };
    float* kgT   = alloc((size_t)256 * 512);
    float* aoT   = alloc((size_t)512 * 512);
    float* Crel  = alloc((size_t)2048 * 256);
    float* Cent  = alloc((size_t)2048 * 256);
    float* brel  = alloc(2048);
    float* bent  = alloc(2048);
    float* bcomb = alloc(512);
    float* Wcomb = alloc((size_t)512 * 512);
    float* relg  = alloc((size_t)200 * 2048);
    float* entg  = alloc((size_t)10000 * 2048);  // 82 MB — the one big table
    float* mctx  = alloc((size_t)PP * 512);
    float* hch   = alloc((size_t)CH_ROWS * 512);
    float* cch   = alloc((size_t)CH_ROWS * 512);
    float* pch   = alloc((size_t)CH_ROWS * 512);
    float* big   = alloc((size_t)CH_ROWS * 2048);  // G / qkv scratch (chunk-local)
    // total ≈ 131 MB < ws_size with margin

    auto gemm = [&](const float* A, int lda, const float* B, int ldb,
                    float* Cp, int ldc, int M, int N, int Kd, const float* bias) {
        dim3 g((unsigned)((N + 63) / 64), (unsigned)((M + 127) / 128));
        gemm_abt<<<g, 256, 0, stream>>>(A, lda, B, ldb, Cp, ldc, M, N, Kd, bias);
    };

    // ---- combined weights (cheap, recomputed every call) ----
    transpose_k<<<dim3(256 / 32, 512 / 32), 256, 0, stream>>>(kg_proj_w, kgT, 512, 256);
    transpose_k<<<dim3(512 / 32, 512 / 32), 256, 0, stream>>>(attn_out_w, aoT, 512, 512);
    // Crel = W_ih[:, :H] @ kg_proj_w ; Cent = W_ih[:, H:] @ kg_proj_w   [2048, 256]
    gemm(w_ih,       1024, kgT, 512, Crel, 256, 2048, 256, 512, nullptr);
    gemm(w_ih + 512, 1024, kgT, 512, Cent, 256, 2048, 256, 512, nullptr);
    // brel = W_ih[:, :H]@kg_proj_b + b_ih + b_hh ; bent = W_ih[:, H:]@kg_proj_b
    rowdot<<<2048 / 4, 256, 0, stream>>>(w_ih,       1024, kg_proj_b, 512, b_ih, b_hh, brel, 2048);
    rowdot<<<2048 / 4, 256, 0, stream>>>(w_ih + 512, 1024, kg_proj_b, 512, nullptr, nullptr, bent, 2048);
    // Wcomb = path_proj_w @ attn_out_w ; bcomb = path_proj_w @ attn_out_b + path_proj_b
    rowdot<<<512 / 4, 256, 0, stream>>>(path_proj_w, 512, attn_out_b, 512, path_proj_b, nullptr, bcomb, 512);
    gemm(path_proj_w, 512, aoT, 512, Wcomb, 512, 512, 512, 512, nullptr);
    // ---- gate tables ----
    gemm(rel_table, 256, Crel, 256, relg, 2048, 200,   2048, 256, brel);
    gemm(ent_table, 256, Cent, 256, entg, 2048, 10000, 2048, 256, bent);

    // ---- chunked pipeline: LSTM (3 steps) -> pemb -> qkv -> attention ----
    for (int ch = 0; ch < N_CHUNK; ++ch) {
        int row0 = ch * CH_ROWS;
        int pair0 = ch * CH_PAIRS;
        // t = 0: h0 = c0 = 0 -> no recurrent GEMM
        lstm_update<<<(CH_ROWS * 128) / 256, 256, 0, stream>>>(
            nullptr, relg, entg, rel_idx, ent_idx, path_lens, hch, cch, pch, 0, row0, CH_ROWS);
        for (int t = 1; t < 3; ++t) {
            gemm(hch, 512, w_hh, 512, big, 2048, CH_ROWS, 2048, 512, nullptr);
            lstm_update<<<(CH_ROWS * 128) / 256, 256, 0, stream>>>(
                big, relg, entg, rel_idx, ent_idx, path_lens, hch, cch, pch, t, row0, CH_ROWS);
        }
        // qkv for this chunk's path embeddings
        gemm(pch, 512, attn_in_w, 512, big, 1536, CH_ROWS, 1536, 512, attn_in_b);
        attn_kernel<<<CH_PAIRS, 256, 0, stream>>>(big, mctx, pair0);
    }

    // ---- out = mctx @ (path_proj_w @ attn_out_w)^T + bcomb ----
    gemm(mctx, 512, Wcomb, 512, out, 512, PP, 512, 512, bcomb);
}

// Round 3
// 1325.161 us; speedup vs baseline: 2.2470x; 2.2470x over previous
//
#include <hip/hip_runtime.h>
#include <cstdint>
#include <cstddef>

#define PP 2048
#define KK 10
#define LL 3
#define EE 256
#define HH 512
#define NPK (PP*KK)      // 20480
#define FOURH (4*HH)     // 2048
#define CH_PAIRS 256
#define CH_ROWS (CH_PAIRS*KK)   // 2560
#define N_CHUNK (PP/CH_PAIRS)   // 8

using f32x4  = __attribute__((ext_vector_type(4))) float;
using short8 = __attribute__((ext_vector_type(8))) short;

__device__ __forceinline__ float sigf(float x) { return 1.0f / (1.0f + expf(-x)); }

__device__ __forceinline__ ushort f2bf(float x) {
    union { float f; uint32_t u; } v; v.f = x;
    uint32_t r = v.u + 0x7FFF + ((v.u >> 16) & 1);
    return (ushort)(r >> 16);
}

#define ACC4(d, s) do { d.x += (s).x; d.y += (s).y; d.z += (s).z; d.w += (s).w; } while (0)

// ---------------- tiled transpose: dst[C][R] = src[R][C] ----------------
__global__ __launch_bounds__(256) void transpose_k(const float* __restrict__ src,
                                                   float* __restrict__ dst, int R, int C) {
    __shared__ float t[32][33];
    int bx = blockIdx.x * 32, by = blockIdx.y * 32;
    int x = threadIdx.x & 31, y = threadIdx.x >> 5;
    for (int i = y; i < 32; i += 8) {
        int r = by + i, c = bx + x;
        if (r < R && c < C) t[i][x] = src[(size_t)r * C + c];
    }
    __syncthreads();
    for (int i = y; i < 32; i += 8) {
        int c = bx + i, r = by + x;
        if (r < R && c < C) dst[(size_t)c * R + r] = t[x][i];
    }
}

// ------------- out[j] = dot(A[j, :Kd], vec) + add1[j] + add2[j] -------------
__global__ __launch_bounds__(256) void rowdot(const float* __restrict__ A, int lda,
                                              const float* __restrict__ vec, int Kd,
                                              const float* __restrict__ add1,
                                              const float* __restrict__ add2,
                                              float* __restrict__ out, int M) {
    int w = threadIdx.x >> 6, lane = threadIdx.x & 63;
    int row = blockIdx.x * 4 + w;
    if (row >= M) return;
    float acc = 0.f;
    for (int k = lane; k < Kd; k += 64) acc += A[(size_t)row * lda + k] * vec[k];
    for (int off = 32; off; off >>= 1) acc += __shfl_down(acc, off, 64);
    if (lane == 0) {
        float r = acc;
        if (add1) r += add1[row];
        if (add2) r += add2[row];
        out[row] = r;
    }
}

// ---------------- fp32 VALU GEMM: C[M,N] = A[M,K] @ B[N,K]^T (+ bias) ----------------
__global__ __launch_bounds__(256) void gemm_abt(
    const float* __restrict__ A, int lda,
    const float* __restrict__ B, int ldb,
    float* __restrict__ C, int ldc,
    int M, int N, int K, const float* __restrict__ bias)
{
    __shared__ float As[16][128];
    __shared__ float Bs[16][64];
    int tid = threadIdx.x;
    int col0 = blockIdx.x * 64;
    int row0 = blockIdx.y * 128;
    int tx = tid & 15, ty = tid >> 4;
    float acc[8][4];
#pragma unroll
    for (int i = 0; i < 8; ++i)
#pragma unroll
        for (int j = 0; j < 4; ++j) acc[i][j] = 0.f;

    int ak4 = tid & 3;
    int arow0 = tid >> 2; // 0..63
    for (int kt = 0; kt < K; kt += 16) {
#pragma unroll
        for (int i = 0; i < 2; ++i) {
            int row = arow0 + i * 64;
            int gr = row0 + row;
            float4 v = make_float4(0.f, 0.f, 0.f, 0.f);
            if (gr < M) v = *reinterpret_cast<const float4*>(A + (size_t)gr * lda + kt + ak4 * 4);
            As[ak4 * 4 + 0][row] = v.x;
            As[ak4 * 4 + 1][row] = v.y;
            As[ak4 * 4 + 2][row] = v.z;
            As[ak4 * 4 + 3][row] = v.w;
        }
        {
            int row = arow0;
            int gc = col0 + row;
            float4 v = make_float4(0.f, 0.f, 0.f, 0.f);
            if (gc < N) v = *reinterpret_cast<const float4*>(B + (size_t)gc * ldb + kt + ak4 * 4);
            Bs[ak4 * 4 + 0][row] = v.x;
            Bs[ak4 * 4 + 1][row] = v.y;
            Bs[ak4 * 4 + 2][row] = v.z;
            Bs[ak4 * 4 + 3][row] = v.w;
        }
        __syncthreads();
#pragma unroll
        for (int kk = 0; kk < 16; ++kk) {
            float4 a0 = *reinterpret_cast<const float4*>(&As[kk][ty * 8]);
            float4 a1 = *reinterpret_cast<const float4*>(&As[kk][ty * 8 + 4]);
            float4 b  = *reinterpret_cast<const float4*>(&Bs[kk][tx * 4]);
            float av[8] = {a0.x, a0.y, a0.z, a0.w, a1.x, a1.y, a1.z, a1.w};
            float bv[4] = {b.x, b.y, b.z, b.w};
#pragma unroll
            for (int i = 0; i < 8; ++i)
#pragma unroll
                for (int j = 0; j < 4; ++j)
                    acc[i][j] += av[i] * bv[j];
        }
        __syncthreads();
    }
    float bb[4] = {0.f, 0.f, 0.f, 0.f};
    if (bias) {
        bb[0] = bias[col0 + tx * 4 + 0];
        bb[1] = bias[col0 + tx * 4 + 1];
        bb[2] = bias[col0 + tx * 4 + 2];
        bb[3] = bias[col0 + tx * 4 + 3];
    }
#pragma unroll
    for (int i = 0; i < 8; ++i) {
        int gr = row0 + ty * 8 + i;
        if (gr < M) {
            float4 o;
            o.x = acc[i][0] + bb[0];
            o.y = acc[i][1] + bb[1];
            o.z = acc[i][2] + bb[2];
            o.w = acc[i][3] + bb[3];
            *reinterpret_cast<float4*>(C + (size_t)gr * ldc + col0 + tx * 4) = o;
        }
    }
}

// ---------------- bf16 MFMA GEMM: C[M,N](f32) = A[M,K]bf16 @ B[N,K]bf16^T (+bias) ----
// 128x128 tile, BK=64, 4 waves (2x2 of 64x64). Requires M%128==0, N%128==0, K%64==0.
// LDS tiles XOR-swizzled (chunk ^= row&7) -> conflict-free ds_read_b128 fragments.
__global__ __launch_bounds__(256) void gemm_bf16(
    const ushort* __restrict__ A, const ushort* __restrict__ B,
    float* __restrict__ C, int M, int N, int K, int ldc,
    const float* __restrict__ bias)
{
    __shared__ ushort As[128 * 64];
    __shared__ ushort Bs[128 * 64];
    int tid = threadIdx.x;
    int lane = tid & 63;
    int w = tid >> 6;
    int wr = w >> 1, wc = w & 1;
    int col0 = blockIdx.x * 128, row0 = blockIdx.y * 128;

    f32x4 acc[4][4];
#pragma unroll
    for (int m = 0; m < 4; ++m)
#pragma unroll
        for (int n = 0; n < 4; ++n) acc[m][n] = {0.f, 0.f, 0.f, 0.f};

    int rA = lane & 15;         // fragment row/col within 16
    int kq = lane >> 4;         // k-quarter (8 bf16 each)

    for (int kt = 0; kt < K; kt += 64) {
        // ---- stage A and B tiles (reg-staged, swizzled ds_write) ----
#pragma unroll
        for (int it = 0; it < 4; ++it) {
            int c = it * 256 + tid;          // chunk id 0..1023
            int row = c >> 3, ch = c & 7;    // 16B chunks per 128B row
            int cs = ch ^ (row & 7);
            uint4 va = *reinterpret_cast<const uint4*>(A + (size_t)(row0 + row) * K + kt + ch * 8);
            *reinterpret_cast<uint4*>(&As[(size_t)row * 64 + cs * 8]) = va;
            uint4 vb = *reinterpret_cast<const uint4*>(B + (size_t)(col0 + row) * K + kt + ch * 8);
            *reinterpret_cast<uint4*>(&Bs[(size_t)row * 64 + cs * 8]) = vb;
        }
        __syncthreads();
        // ---- compute: 2 k-steps of 32 ----
#pragma unroll
        for (int s = 0; s < 2; ++s) {
            int kb = s * 4;
            int csw = (kb + kq) ^ (rA & 7);
            short8 af[4], bfr[4];
#pragma unroll
            for (int m = 0; m < 4; ++m) {
                int rowA = wr * 64 + m * 16 + rA;
                af[m] = *reinterpret_cast<const short8*>(&As[(size_t)rowA * 64 + csw * 8]);
            }
#pragma unroll
            for (int n = 0; n < 4; ++n) {
                int rowB = wc * 64 + n * 16 + rA;
                bfr[n] = *reinterpret_cast<const short8*>(&Bs[(size_t)rowB * 64 + csw * 8]);
            }
#pragma unroll
            for (int m = 0; m < 4; ++m)
#pragma unroll
                for (int n = 0; n < 4; ++n)
                    acc[m][n] = __builtin_amdgcn_mfma_f32_16x16x32_bf16(af[m], bfr[n], acc[m][n], 0, 0, 0);
        }
        __syncthreads();
    }
    // ---- epilogue: C col = lane&15, row = (lane>>4)*4 + reg ----
#pragma unroll
    for (int n = 0; n < 4; ++n) {
        int gcol = col0 + wc * 64 + n * 16 + rA;
        float bv = bias ? bias[gcol] : 0.f;
#pragma unroll
        for (int m = 0; m < 4; ++m) {
            int grow0 = row0 + wr * 64 + m * 16 + kq * 4;
#pragma unroll
            for (int r = 0; r < 4; ++r)
                C[(size_t)(grow0 + r) * ldc + gcol] = acc[m][n][r] + bv;
        }
    }
}

// ---------------- fp32 -> bf16 bulk convert (n % 4 == 0) ----------------
__global__ __launch_bounds__(256) void f2bf_k(const float* __restrict__ s,
                                              ushort* __restrict__ d, int n4) {
    int i = blockIdx.x * 256 + threadIdx.x;
    if (i < n4) {
        float4 v = reinterpret_cast<const float4*>(s)[i];
        ushort4 u = make_ushort4(f2bf(v.x), f2bf(v.y), f2bf(v.z), f2bf(v.w));
        reinterpret_cast<ushort4*>(d)[i] = u;
    }
}

// ---------------- LSTM pointwise: gates from gathered tables (+ G) ----------------
// h (bf16) / c (fp32) / pemb (bf16) are CHUNK-LOCAL; idx/lens global via row0.
__global__ __launch_bounds__(256) void lstm_update(
    const float* __restrict__ G,
    const float* __restrict__ relg, const float* __restrict__ entg,
    const int* __restrict__ rel_idx, const int* __restrict__ ent_idx,
    const int* __restrict__ lens_,
    ushort* __restrict__ hbuf, float* __restrict__ cbuf, ushort* __restrict__ pemb,
    int t, int row0, int nrows)
{
    int gid = blockIdx.x * 256 + threadIdx.x;
    if (gid >= nrows * 128) return;
    int nl = gid >> 7, j4 = gid & 127;
    int n = row0 + nl;
    int r = rel_idx[n * 3 + t];
    int e = ent_idx[n * 3 + t];
    const float4* rg = reinterpret_cast<const float4*>(relg + (size_t)r * FOURH);
    const float4* eg = reinterpret_cast<const float4*>(entg + (size_t)e * FOURH);
    float4 gi = rg[j4], gf = rg[j4 + 128], gg = rg[j4 + 256], go = rg[j4 + 384];
    float4 e0 = eg[j4], e1 = eg[j4 + 128], e2 = eg[j4 + 256], e3 = eg[j4 + 384];
    ACC4(gi, e0); ACC4(gf, e1); ACC4(gg, e2); ACC4(go, e3);
    if (G) {
        const float4* gp = reinterpret_cast<const float4*>(G + (size_t)nl * FOURH);
        float4 a0 = gp[j4], a1 = gp[j4 + 128], a2 = gp[j4 + 256], a3 = gp[j4 + 384];
        ACC4(gi, a0); ACC4(gf, a1); ACC4(gg, a2); ACC4(go, a3);
    }
    float4 cold = make_float4(0.f, 0.f, 0.f, 0.f);
    if (t > 0) cold = reinterpret_cast<const float4*>(cbuf)[(size_t)nl * 128 + j4];
    float4 cn, hn;
    cn.x = sigf(gf.x) * cold.x + sigf(gi.x) * tanhf(gg.x); hn.x = sigf(go.x) * tanhf(cn.x);
    cn.y = sigf(gf.y) * cold.y + sigf(gi.y) * tanhf(gg.y); hn.y = sigf(go.y) * tanhf(cn.y);
    cn.z = sigf(gf.z) * cold.z + sigf(gi.z) * tanhf(gg.z); hn.z = sigf(go.z) * tanhf(cn.z);
    cn.w = sigf(gf.w) * cold.w + sigf(gi.w) * tanhf(gg.w); hn.w = sigf(go.w) * tanhf(cn.w);
    reinterpret_cast<float4*>(cbuf)[(size_t)nl * 128 + j4] = cn;
    ushort4 hu = make_ushort4(f2bf(hn.x), f2bf(hn.y), f2bf(hn.z), f2bf(hn.w));
    *reinterpret_cast<ushort4*>(&hbuf[(size_t)nl * 512 + j4 * 4]) = hu;
    int len = lens_[n];
    int last = len - 1;
    if (last < 0) last = 0;
    if (last > 2) last = 2;
    if (last == t) {
        ushort4 pv = make_ushort4(0, 0, 0, 0);
        if (len > 0) pv = hu;
        *reinterpret_cast<ushort4*>(&pemb[(size_t)nl * 512 + j4 * 4]) = pv;
    }
}

// ---------------- per-pair attention -> mean-over-q context ----------------
__global__ __launch_bounds__(256) void attn_kernel(const float* __restrict__ qkv,
                                                   float* __restrict__ mctx, int pair0)
{
    __shared__ float qk[10][1024];
    __shared__ float sc[4][10][10];
    __shared__ float wb[4][10];
    int tid = threadIdx.x;
    const float* base = qkv + (size_t)blockIdx.x * 10 * 1536;
    for (int i = tid; i < 2560; i += 256) {
        int row = i >> 8, c4 = i & 255;
        reinterpret_cast<float4*>(&qk[row][0])[c4] =
            reinterpret_cast<const float4*>(base + (size_t)row * 1536)[c4];
    }
    __syncthreads();
    const float scale = 0.08838834764831845f; // 1/sqrt(128)
    for (int idx = tid; idx < 400; idx += 256) {
        int h = idx / 100, rem = idx % 100, qi = rem / 10, ki = rem % 10;
        const float* qp = &qk[qi][h * 128];
        const float* kp = &qk[ki][512 + h * 128];
        float a = 0.f;
        for (int d = 0; d < 128; ++d) a += qp[d] * kp[d];
        sc[h][qi][ki] = a * scale;
    }
    __syncthreads();
    if (tid < 40) {
        int h = tid / 10, qi = tid % 10;
        float m = -1e30f;
        for (int ki = 0; ki < 10; ++ki) m = fmaxf(m, sc[h][qi][ki]);
        float ex[10]; float s = 0.f;
        for (int ki = 0; ki < 10; ++ki) { ex[ki] = expf(sc[h][qi][ki] - m); s += ex[ki]; }
        float inv = 1.f / s;
        for (int ki = 0; ki < 10; ++ki) sc[h][qi][ki] = ex[ki] * inv;
    }
    __syncthreads();
    if (tid < 40) {
        int h = tid / 10, ki = tid % 10;
        float s = 0.f;
        for (int qi = 0; qi < 10; ++qi) s += sc[h][qi][ki];
        wb[h][ki] = s * 0.1f;
    }
    __syncthreads();
    for (int e = tid; e < 512; e += 256) {
        int h = e >> 7, d = e & 127;
        float a = 0.f;
        for (int ki = 0; ki < 10; ++ki)
            a += wb[h][ki] * base[(size_t)ki * 1536 + 1024 + h * 128 + d];
        mctx[(size_t)(pair0 + blockIdx.x) * 512 + e] = a;
    }
}

extern "C" void kernel_launch(void* const* d_in, const int* in_sizes, int n_in,
                              void* d_out, int out_size, void* d_ws, size_t ws_size,
                              hipStream_t stream)
{
    const int* rel_idx     = (const int*)d_in[0];
    const int* ent_idx     = (const int*)d_in[1];
    const int* path_lens   = (const int*)d_in[2];
    const float* rel_table = (const float*)d_in[3];
    const float* ent_table = (const float*)d_in[4];
    const float* kg_proj_w = (const float*)d_in[5];
    const float* kg_proj_b = (const float*)d_in[6];
    const float* w_ih      = (const float*)d_in[7];
    const float* w_hh      = (const float*)d_in[8];
    const float* b_ih      = (const float*)d_in[9];
    const float* b_hh      = (const float*)d_in[10];
    const float* attn_in_w = (const float*)d_in[11];
    const float* attn_in_b = (const float*)d_in[12];
    const float* attn_out_w = (const float*)d_in[13];
    const float* attn_out_b = (const float*)d_in[14];
    const float* path_proj_w = (const float*)d_in[15];
    const float* path_proj_b = (const float*)d_in[16];
    float* out = (float*)d_out;
    (void)in_sizes; (void)n_in; (void)out_size; (void)ws_size;

    float* ws = (float*)d_ws;
    size_t off = 0;
    auto alloc = [&](size_t n) { float* p = ws + off; off += (n + 63) & ~(size_t)63; return p; };
    auto allocu = [&](size_t n) { return (ushort*)alloc((n + 1) / 2); };
    float* kgT   = alloc((size_t)256 * 512);
    float* aoT   = alloc((size_t)512 * 512);
    float* Crel  = alloc((size_t)2048 * 256);
    float* Cent  = alloc((size_t)2048 * 256);
    float* brel  = alloc(2048);
    float* bent  = alloc(2048);
    float* bcomb = alloc(512);
    float* Wcomb = alloc((size_t)512 * 512);
    float* relg  = alloc((size_t)200 * 2048);
    float* entg  = alloc((size_t)10000 * 2048);  // 82 MB
    float* mctx  = alloc((size_t)PP * 512);
    float* cch   = alloc((size_t)CH_ROWS * 512);
    float* big   = alloc((size_t)CH_ROWS * 2048);  // G / qkv scratch
    ushort* whhB = allocu((size_t)2048 * 512);
    ushort* aiwB = allocu((size_t)1536 * 512);
    ushort* hch  = allocu((size_t)CH_ROWS * 512);
    ushort* pch  = allocu((size_t)CH_ROWS * 512);
    // total ~130 MB (same budget that passed in round 2)

    auto gemm = [&](const float* A, int lda, const float* B, int ldb,
                    float* Cp, int ldc, int M, int N, int Kd, const float* bias) {
        dim3 g((unsigned)((N + 63) / 64), (unsigned)((M + 127) / 128));
        gemm_abt<<<g, 256, 0, stream>>>(A, lda, B, ldb, Cp, ldc, M, N, Kd, bias);
    };
    auto gemmB = [&](const ushort* A, const ushort* B, float* Cp,
                     int M, int N, int Kd, const float* bias) {
        dim3 g((unsigned)(N / 128), (unsigned)(M / 128));
        gemm_bf16<<<g, 256, 0, stream>>>(A, B, Cp, M, N, Kd, N, bias);
    };

    // ---- combined weights ----
    transpose_k<<<dim3(256 / 32, 512 / 32), 256, 0, stream>>>(kg_proj_w, kgT, 512, 256);
    transpose_k<<<dim3(512 / 32, 512 / 32), 256, 0, stream>>>(attn_out_w, aoT, 512, 512);
    gemm(w_ih,       1024, kgT, 512, Crel, 256, 2048, 256, 512, nullptr);
    gemm(w_ih + 512, 1024, kgT, 512, Cent, 256, 2048, 256, 512, nullptr);
    rowdot<<<2048 / 4, 256, 0, stream>>>(w_ih,       1024, kg_proj_b, 512, b_ih, b_hh, brel, 2048);
    rowdot<<<2048 / 4, 256, 0, stream>>>(w_ih + 512, 1024, kg_proj_b, 512, nullptr, nullptr, bent, 2048);
    rowdot<<<512 / 4, 256, 0, stream>>>(path_proj_w, 512, attn_out_b, 512, path_proj_b, nullptr, bcomb, 512);
    gemm(path_proj_w, 512, aoT, 512, Wcomb, 512, 512, 512, 512, nullptr);
    // ---- gate tables (fp32 — dominant gate term stays exact) ----
    gemm(rel_table, 256, Crel, 256, relg, 2048, 200,   2048, 256, brel);
    gemm(ent_table, 256, Cent, 256, entg, 2048, 10000, 2048, 256, bent);
    // ---- bf16 weight copies ----
    f2bf_k<<<(2048 * 512 / 4 + 255) / 256, 256, 0, stream>>>(w_hh, whhB, 2048 * 512 / 4);
    f2bf_k<<<(1536 * 512 / 4 + 255) / 256, 256, 0, stream>>>(attn_in_w, aiwB, 1536 * 512 / 4);

    // ---- chunked pipeline: LSTM (3 steps) -> pemb -> qkv -> attention ----
    for (int ch = 0; ch < N_CHUNK; ++ch) {
        int row0 = ch * CH_ROWS;
        int pair0 = ch * CH_PAIRS;
        lstm_update<<<(CH_ROWS * 128) / 256, 256, 0, stream>>>(
            nullptr, relg, entg, rel_idx, ent_idx, path_lens, hch, cch, pch, 0, row0, CH_ROWS);
        for (int t = 1; t < 3; ++t) {
            gemmB(hch, whhB, big, CH_ROWS, 2048, 512, nullptr);
            lstm_update<<<(CH_ROWS * 128) / 256, 256, 0, stream>>>(
                big, relg, entg, rel_idx, ent_idx, path_lens, hch, cch, pch, t, row0, CH_ROWS);
        }
        gemmB(pch, aiwB, big, CH_ROWS, 1536, 512, attn_in_b);
        attn_kernel<<<CH_PAIRS, 256, 0, stream>>>(big, mctx, pair0);
    }

    // ---- out = mctx @ (path_proj_w @ attn_out_w)^T + bcomb (fp32) ----
    gemm(mctx, 512, Wcomb, 512, out, 512, PP, 512, 512, bcomb);
}

// Round 5
// 1195.097 us; speedup vs baseline: 2.4915x; 1.1088x over previous
//
#include <hip/hip_runtime.h>
#include <cstdint>
#include <cstddef>

#define PP 2048
#define KK 10
#define LL 3
#define EE 256
#define HH 512
#define NPK (PP*KK)      // 20480
#define FOURH (4*HH)     // 2048
#define CH_PAIRS 256
#define CH_ROWS (CH_PAIRS*KK)   // 2560
#define N_CHUNK (PP/CH_PAIRS)   // 8
#define ENT_PAD 10112            // 79*128
#define REL_PAD 256

using f32x4  = __attribute__((ext_vector_type(4))) float;
using short8 = __attribute__((ext_vector_type(8))) short;

__device__ __forceinline__ float sigf(float x) { return 1.0f / (1.0f + expf(-x)); }

__device__ __forceinline__ ushort f2bf(float x) {
    union { float f; uint32_t u; } v; v.f = x;
    uint32_t r = v.u + 0x7FFF + ((v.u >> 16) & 1);
    return (ushort)(r >> 16);
}
__device__ __forceinline__ float bf2f(ushort u) {
    union { uint32_t u; float f; } v; v.u = ((uint32_t)u) << 16;
    return v.f;
}

// perm[p] = old gate row index for new (permuted) row p.
// p = uh*64 + g*16 + ul  (unit u = uh*16+ul),  old = g*512 + u
__global__ __launch_bounds__(256) void make_perm(int* __restrict__ perm) {
    int p = blockIdx.x * 256 + threadIdx.x;
    if (p < 2048) {
        int uh = p >> 6, g = (p >> 4) & 3, ul = p & 15;
        perm[p] = g * 512 + uh * 16 + ul;
    }
}

// ---------------- tiled transpose: dst[C][R] = src[R][C] ----------------
__global__ __launch_bounds__(256) void transpose_k(const float* __restrict__ src,
                                                   float* __restrict__ dst, int R, int C) {
    __shared__ float t[32][33];
    int bx = blockIdx.x * 32, by = blockIdx.y * 32;
    int x = threadIdx.x & 31, y = threadIdx.x >> 5;
    for (int i = y; i < 32; i += 8) {
        int r = by + i, c = bx + x;
        if (r < R && c < C) t[i][x] = src[(size_t)r * C + c];
    }
    __syncthreads();
    for (int i = y; i < 32; i += 8) {
        int c = bx + i, r = by + x;
        if (r < R && c < C) dst[(size_t)c * R + r] = t[x][i];
    }
}

// ------------- out[row] = dot(A[perm(row), :Kd], vec) + add1 + add2 -------------
__global__ __launch_bounds__(256) void rowdot(const float* __restrict__ A, int lda,
                                              const float* __restrict__ vec, int Kd,
                                              const float* __restrict__ add1,
                                              const float* __restrict__ add2,
                                              float* __restrict__ out, int M,
                                              const int* __restrict__ perm) {
    int w = threadIdx.x >> 6, lane = threadIdx.x & 63;
    int row = blockIdx.x * 4 + w;
    if (row >= M) return;
    int ar = perm ? perm[row] : row;
    float acc = 0.f;
    for (int k = lane; k < Kd; k += 64) acc += A[(size_t)ar * lda + k] * vec[k];
    for (int off = 32; off; off >>= 1) acc += __shfl_down(acc, off, 64);
    if (lane == 0) {
        float r = acc;
        if (add1) r += add1[ar];
        if (add2) r += add2[ar];
        out[row] = r;
    }
}

// ---------------- fp32 VALU GEMM: C[M,N] = A[aperm(M),K] @ B[N,K]^T (+ bias) --------
__global__ __launch_bounds__(256) void gemm_abt(
    const float* __restrict__ A, int lda,
    const float* __restrict__ B, int ldb,
    float* __restrict__ C, int ldc,
    int M, int N, int K, const float* __restrict__ bias,
    const int* __restrict__ aperm)
{
    __shared__ float As[16][128];
    __shared__ float Bs[16][64];
    int tid = threadIdx.x;
    int col0 = blockIdx.x * 64;
    int row0 = blockIdx.y * 128;
    int tx = tid & 15, ty = tid >> 4;
    float acc[8][4];
#pragma unroll
    for (int i = 0; i < 8; ++i)
#pragma unroll
        for (int j = 0; j < 4; ++j) acc[i][j] = 0.f;

    int ak4 = tid & 3;
    int arow0 = tid >> 2; // 0..63
    for (int kt = 0; kt < K; kt += 16) {
#pragma unroll
        for (int i = 0; i < 2; ++i) {
            int row = arow0 + i * 64;
            int gr = row0 + row;
            float4 v = make_float4(0.f, 0.f, 0.f, 0.f);
            if (gr < M) {
                int sr = aperm ? aperm[gr] : gr;
                v = *reinterpret_cast<const float4*>(A + (size_t)sr * lda + kt + ak4 * 4);
            }
            As[ak4 * 4 + 0][row] = v.x;
            As[ak4 * 4 + 1][row] = v.y;
            As[ak4 * 4 + 2][row] = v.z;
            As[ak4 * 4 + 3][row] = v.w;
        }
        {
            int row = arow0;
            int gc = col0 + row;
            float4 v = make_float4(0.f, 0.f, 0.f, 0.f);
            if (gc < N) v = *reinterpret_cast<const float4*>(B + (size_t)gc * ldb + kt + ak4 * 4);
            Bs[ak4 * 4 + 0][row] = v.x;
            Bs[ak4 * 4 + 1][row] = v.y;
            Bs[ak4 * 4 + 2][row] = v.z;
            Bs[ak4 * 4 + 3][row] = v.w;
        }
        __syncthreads();
#pragma unroll
        for (int kk = 0; kk < 16; ++kk) {
            float4 a0 = *reinterpret_cast<const float4*>(&As[kk][ty * 8]);
            float4 a1 = *reinterpret_cast<const float4*>(&As[kk][ty * 8 + 4]);
            float4 b  = *reinterpret_cast<const float4*>(&Bs[kk][tx * 4]);
            float av[8] = {a0.x, a0.y, a0.z, a0.w, a1.x, a1.y, a1.z, a1.w};
            float bv[4] = {b.x, b.y, b.z, b.w};
#pragma unroll
            for (int i = 0; i < 8; ++i)
#pragma unroll
                for (int j = 0; j < 4; ++j)
                    acc[i][j] += av[i] * bv[j];
        }
        __syncthreads();
    }
    float bb[4] = {0.f, 0.f, 0.f, 0.f};
    if (bias) {
        bb[0] = bias[col0 + tx * 4 + 0];
        bb[1] = bias[col0 + tx * 4 + 1];
        bb[2] = bias[col0 + tx * 4 + 2];
        bb[3] = bias[col0 + tx * 4 + 3];
    }
#pragma unroll
    for (int i = 0; i < 8; ++i) {
        int gr = row0 + ty * 8 + i;
        if (gr < M) {
            float4 o;
            o.x = acc[i][0] + bb[0];
            o.y = acc[i][1] + bb[1];
            o.z = acc[i][2] + bb[2];
            o.w = acc[i][3] + bb[3];
            *reinterpret_cast<float4*>(C + (size_t)gr * ldc + col0 + tx * 4) = o;
        }
    }
}

// ---------------- bf16 MFMA GEMM: C[M,N](f32) = A@B^T (+bias). M,N%128==0, K%64==0 ----
__global__ __launch_bounds__(256) void gemm_bf16(
    const ushort* __restrict__ A, const ushort* __restrict__ B,
    float* __restrict__ C, int M, int N, int K, int ldc,
    const float* __restrict__ bias)
{
    __shared__ ushort As[128 * 64];
    __shared__ ushort Bs[128 * 64];
    int tid = threadIdx.x;
    int lane = tid & 63;
    int w = tid >> 6;
    int wr = w >> 1, wc = w & 1;
    int col0 = blockIdx.x * 128, row0 = blockIdx.y * 128;

    f32x4 acc[4][4];
#pragma unroll
    for (int m = 0; m < 4; ++m)
#pragma unroll
        for (int n = 0; n < 4; ++n) acc[m][n] = {0.f, 0.f, 0.f, 0.f};

    int rA = lane & 15;
    int kq = lane >> 4;

    for (int kt = 0; kt < K; kt += 64) {
#pragma unroll
        for (int it = 0; it < 4; ++it) {
            int c = it * 256 + tid;
            int row = c >> 3, ch = c & 7;
            int cs = ch ^ (row & 7);
            uint4 va = *reinterpret_cast<const uint4*>(A + (size_t)(row0 + row) * K + kt + ch * 8);
            *reinterpret_cast<uint4*>(&As[(size_t)row * 64 + cs * 8]) = va;
            uint4 vb = *reinterpret_cast<const uint4*>(B + (size_t)(col0 + row) * K + kt + ch * 8);
            *reinterpret_cast<uint4*>(&Bs[(size_t)row * 64 + cs * 8]) = vb;
        }
        __syncthreads();
#pragma unroll
        for (int s = 0; s < 2; ++s) {
            int csw = (s * 4 + kq) ^ (rA & 7);
            short8 af[4], bfr[4];
#pragma unroll
            for (int m = 0; m < 4; ++m) {
                int rowA = wr * 64 + m * 16 + rA;
                af[m] = *reinterpret_cast<const short8*>(&As[(size_t)rowA * 64 + csw * 8]);
            }
#pragma unroll
            for (int n = 0; n < 4; ++n) {
                int rowB = wc * 64 + n * 16 + rA;
                bfr[n] = *reinterpret_cast<const short8*>(&Bs[(size_t)rowB * 64 + csw * 8]);
            }
#pragma unroll
            for (int m = 0; m < 4; ++m)
#pragma unroll
                for (int n = 0; n < 4; ++n)
                    acc[m][n] = __builtin_amdgcn_mfma_f32_16x16x32_bf16(af[m], bfr[n], acc[m][n], 0, 0, 0);
        }
        __syncthreads();
    }
#pragma unroll
    for (int n = 0; n < 4; ++n) {
        int gcol = col0 + wc * 64 + n * 16 + rA;
        float bv = bias ? bias[gcol] : 0.f;
#pragma unroll
        for (int m = 0; m < 4; ++m) {
            int grow0 = row0 + wr * 64 + m * 16 + kq * 4;
#pragma unroll
            for (int r = 0; r < 4; ++r)
                C[(size_t)(grow0 + r) * ldc + gcol] = acc[m][n][r] + bv;
        }
    }
}

// ------------- split-bf16 GEMM (fp32-accuracy): C = Ah.Bh^T + Ah.Bl^T + Al.Bh^T + bias
__global__ __launch_bounds__(256) void gemm_bf16s(
    const ushort* __restrict__ Ah, const ushort* __restrict__ Al,
    const ushort* __restrict__ Bh, const ushort* __restrict__ Bl,
    float* __restrict__ C, int M, int N, int K, int ldc,
    const float* __restrict__ bias)
{
    __shared__ ushort Ash[128 * 64];
    __shared__ ushort Asl[128 * 64];
    __shared__ ushort Bsh[128 * 64];
    __shared__ ushort Bsl[128 * 64];
    int tid = threadIdx.x;
    int lane = tid & 63;
    int w = tid >> 6;
    int wr = w >> 1, wc = w & 1;
    int col0 = blockIdx.x * 128, row0 = blockIdx.y * 128;

    f32x4 acc[4][4];
#pragma unroll
    for (int m = 0; m < 4; ++m)
#pragma unroll
        for (int n = 0; n < 4; ++n) acc[m][n] = {0.f, 0.f, 0.f, 0.f};

    int rA = lane & 15;
    int kq = lane >> 4;

    for (int kt = 0; kt < K; kt += 64) {
#pragma unroll
        for (int it = 0; it < 4; ++it) {
            int c = it * 256 + tid;
            int row = c >> 3, ch = c & 7;
            int cs = ch ^ (row & 7);
            size_t ga = (size_t)(row0 + row) * K + kt + ch * 8;
            size_t gb = (size_t)(col0 + row) * K + kt + ch * 8;
            size_t la = (size_t)row * 64 + cs * 8;
            *reinterpret_cast<uint4*>(&Ash[la]) = *reinterpret_cast<const uint4*>(Ah + ga);
            *reinterpret_cast<uint4*>(&Asl[la]) = *reinterpret_cast<const uint4*>(Al + ga);
            *reinterpret_cast<uint4*>(&Bsh[la]) = *reinterpret_cast<const uint4*>(Bh + gb);
            *reinterpret_cast<uint4*>(&Bsl[la]) = *reinterpret_cast<const uint4*>(Bl + gb);
        }
        __syncthreads();
#pragma unroll
        for (int s = 0; s < 2; ++s) {
            int csw = (s * 4 + kq) ^ (rA & 7);
            short8 xh[4], yh[4], t4[4];
#pragma unroll
            for (int m = 0; m < 4; ++m) {
                int rowA = wr * 64 + m * 16 + rA;
                xh[m] = *reinterpret_cast<const short8*>(&Ash[(size_t)rowA * 64 + csw * 8]);
            }
#pragma unroll
            for (int n = 0; n < 4; ++n) {
                int rowB = wc * 64 + n * 16 + rA;
                yh[n] = *reinterpret_cast<const short8*>(&Bsh[(size_t)rowB * 64 + csw * 8]);
            }
#pragma unroll
            for (int m = 0; m < 4; ++m)
#pragma unroll
                for (int n = 0; n < 4; ++n)
                    acc[m][n] = __builtin_amdgcn_mfma_f32_16x16x32_bf16(xh[m], yh[n], acc[m][n], 0, 0, 0);
            // + Ah . Bl
#pragma unroll
            for (int n = 0; n < 4; ++n) {
                int rowB = wc * 64 + n * 16 + rA;
                t4[n] = *reinterpret_cast<const short8*>(&Bsl[(size_t)rowB * 64 + csw * 8]);
            }
#pragma unroll
            for (int m = 0; m < 4; ++m)
#pragma unroll
                for (int n = 0; n < 4; ++n)
                    acc[m][n] = __builtin_amdgcn_mfma_f32_16x16x32_bf16(xh[m], t4[n], acc[m][n], 0, 0, 0);
            // + Al . Bh
#pragma unroll
            for (int m = 0; m < 4; ++m) {
                int rowA = wr * 64 + m * 16 + rA;
                t4[m] = *reinterpret_cast<const short8*>(&Asl[(size_t)rowA * 64 + csw * 8]);
            }
#pragma unroll
            for (int m = 0; m < 4; ++m)
#pragma unroll
                for (int n = 0; n < 4; ++n)
                    acc[m][n] = __builtin_amdgcn_mfma_f32_16x16x32_bf16(t4[m], yh[n], acc[m][n], 0, 0, 0);
        }
        __syncthreads();
    }
#pragma unroll
    for (int n = 0; n < 4; ++n) {
        int gcol = col0 + wc * 64 + n * 16 + rA;
        float bv = bias ? bias[gcol] : 0.f;
#pragma unroll
        for (int m = 0; m < 4; ++m) {
            int grow0 = row0 + wr * 64 + m * 16 + kq * 4;
#pragma unroll
            for (int r = 0; r < 4; ++r)
                C[(size_t)(grow0 + r) * ldc + gcol] = acc[m][n][r] + bv;
        }
    }
}

// ---------------- FUSED: G = A(h_in)@whhB^T, then LSTM pointwise in epilogue --------
// Fixed M=CH_ROWS(2560), N=2048(perm gate layout), K=512. grid (16, 20).
// h ping-pong: A (h at step t-1) and hbuf (h at step t) MUST be different buffers —
// blocks with the same by but different bx read the same A rows while others write.
__global__ __launch_bounds__(256) void gemm_lstm(
    const ushort* __restrict__ A, const ushort* __restrict__ B,
    const float* __restrict__ relg, const float* __restrict__ entg,
    const int* __restrict__ rel_idx, const int* __restrict__ ent_idx,
    const int* __restrict__ lens_,
    ushort* __restrict__ hbuf, float* __restrict__ cbuf, ushort* __restrict__ pemb,
    int t, int row0_glob)
{
    __shared__ ushort As[128 * 64];
    __shared__ ushort Bs[128 * 64];
    const int K = 512;
    int tid = threadIdx.x;
    int lane = tid & 63;
    int w = tid >> 6;
    int wr = w >> 1, wc = w & 1;
    int col0 = blockIdx.x * 128, row0 = blockIdx.y * 128;

    f32x4 acc[4][4];
#pragma unroll
    for (int m = 0; m < 4; ++m)
#pragma unroll
        for (int n = 0; n < 4; ++n) acc[m][n] = {0.f, 0.f, 0.f, 0.f};

    int rA = lane & 15;
    int kq = lane >> 4;

    for (int kt = 0; kt < K; kt += 64) {
#pragma unroll
        for (int it = 0; it < 4; ++it) {
            int c = it * 256 + tid;
            int row = c >> 3, ch = c & 7;
            int cs = ch ^ (row & 7);
            uint4 va = *reinterpret_cast<const uint4*>(A + (size_t)(row0 + row) * K + kt + ch * 8);
            *reinterpret_cast<uint4*>(&As[(size_t)row * 64 + cs * 8]) = va;
            uint4 vb = *reinterpret_cast<const uint4*>(B + (size_t)(col0 + row) * K + kt + ch * 8);
            *reinterpret_cast<uint4*>(&Bs[(size_t)row * 64 + cs * 8]) = vb;
        }
        __syncthreads();
#pragma unroll
        for (int s = 0; s < 2; ++s) {
            int csw = (s * 4 + kq) ^ (rA & 7);
            short8 af[4], bfr[4];
#pragma unroll
            for (int m = 0; m < 4; ++m) {
                int rowA = wr * 64 + m * 16 + rA;
                af[m] = *reinterpret_cast<const short8*>(&As[(size_t)rowA * 64 + csw * 8]);
            }
#pragma unroll
            for (int n = 0; n < 4; ++n) {
                int rowB = wc * 64 + n * 16 + rA;
                bfr[n] = *reinterpret_cast<const short8*>(&Bs[(size_t)rowB * 64 + csw * 8]);
            }
#pragma unroll
            for (int m = 0; m < 4; ++m)
#pragma unroll
                for (int n = 0; n < 4; ++n)
                    acc[m][n] = __builtin_amdgcn_mfma_f32_16x16x32_bf16(af[m], bfr[n], acc[m][n], 0, 0, 0);
        }
        __syncthreads();
    }

    // ---- fused LSTM epilogue ----
    // col = col0 + wc*64 + g*16 + rA  ->  this lane owns unit u = uh*16+rA, uh = bx*2+wc
    int uh = blockIdx.x * 2 + wc;
    int u  = uh * 16 + rA;
    int colbase = uh * 64 + rA;   // offset of gate 0 in permuted 2048-layout
#pragma unroll
    for (int m = 0; m < 4; ++m) {
#pragma unroll
        for (int r = 0; r < 4; ++r) {
            int rl = wr * 64 + m * 16 + kq * 4 + r;   // chunk-local row
            int n  = row0_glob + row0 + rl;           // global path row
            int nl = row0 + rl;
            int ri = rel_idx[n * 3 + t];
            int ei = ent_idx[n * 3 + t];
            const float* rr = relg + (size_t)ri * 2048 + colbase;
            const float* er = entg + (size_t)ei * 2048 + colbase;
            float gi = acc[m][0][r] + rr[0]  + er[0];
            float gf = acc[m][1][r] + rr[16] + er[16];
            float gg = acc[m][2][r] + rr[32] + er[32];
            float go = acc[m][3][r] + rr[48] + er[48];
            float cold = cbuf[(size_t)nl * 512 + u];
            float cn = sigf(gf) * cold + sigf(gi) * tanhf(gg);
            float hn = sigf(go) * tanhf(cn);
            cbuf[(size_t)nl * 512 + u] = cn;
            ushort hu = f2bf(hn);
            hbuf[(size_t)nl * 512 + u] = hu;
            int len = lens_[n];
            int last = len - 1;
            if (last < 0) last = 0;
            if (last > 2) last = 2;
            if (last == t) pemb[(size_t)nl * 512 + u] = (len > 0) ? hu : (ushort)0;
        }
    }
}

// ---------------- fp32 -> bf16 bulk convert (n % 4 == 0) ----------------
__global__ __launch_bounds__(256) void f2bf_k(const float* __restrict__ s,
                                              ushort* __restrict__ d, int n4) {
    int i = blockIdx.x * 256 + threadIdx.x;
    if (i < n4) {
        float4 v = reinterpret_cast<const float4*>(s)[i];
        ushort4 u = make_ushort4(f2bf(v.x), f2bf(v.y), f2bf(v.z), f2bf(v.w));
        reinterpret_cast<ushort4*>(d)[i] = u;
    }
}

// ---- fp32 -> (hi,lo) bf16 split with zero tail padding; counts in float4s ----
__global__ __launch_bounds__(256) void f2bf_split(const float* __restrict__ s,
                                                  ushort* __restrict__ hi,
                                                  ushort* __restrict__ lo,
                                                  int nsrc4, int ndst4) {
    int i = blockIdx.x * 256 + threadIdx.x;
    if (i >= ndst4) return;
    ushort4 h = make_ushort4(0, 0, 0, 0), l = make_ushort4(0, 0, 0, 0);
    if (i < nsrc4) {
        float4 v = reinterpret_cast<const float4*>(s)[i];
        h = make_ushort4(f2bf(v.x), f2bf(v.y), f2bf(v.z), f2bf(v.w));
        l = make_ushort4(f2bf(v.x - bf2f(h.x)), f2bf(v.y - bf2f(h.y)),
                         f2bf(v.z - bf2f(h.z)), f2bf(v.w - bf2f(h.w)));
    }
    reinterpret_cast<ushort4*>(hi)[i] = h;
    reinterpret_cast<ushort4*>(lo)[i] = l;
}

// ---- permuted-row fp32 -> bf16 (w_hh -> whhB), ncols % 4 == 0 ----
__global__ __launch_bounds__(256) void f2bf_perm_rows(const float* __restrict__ s,
                                                      ushort* __restrict__ d,
                                                      const int* __restrict__ perm,
                                                      int nrows, int ncols4) {
    int i = blockIdx.x * 256 + threadIdx.x;
    if (i >= nrows * ncols4) return;
    int row = i / ncols4, c4 = i % ncols4;
    int sr = perm[row];
    float4 v = reinterpret_cast<const float4*>(s + (size_t)sr * ncols4 * 4)[c4];
    ushort4 u = make_ushort4(f2bf(v.x), f2bf(v.y), f2bf(v.z), f2bf(v.w));
    reinterpret_cast<ushort4*>(d + (size_t)row * ncols4 * 4)[c4] = u;
}

// ---------------- LSTM t=0 (no recurrent term), permuted gate tables ----------------
__global__ __launch_bounds__(256) void lstm_t0(
    const float* __restrict__ relg, const float* __restrict__ entg,
    const int* __restrict__ rel_idx, const int* __restrict__ ent_idx,
    const int* __restrict__ lens_,
    ushort* __restrict__ hbuf, float* __restrict__ cbuf, ushort* __restrict__ pemb,
    int row0, int nrows)
{
    int gid = blockIdx.x * 256 + threadIdx.x;
    if (gid >= nrows * 128) return;
    int nl = gid >> 7, q = gid & 127;
    int uh = q >> 2, ul4 = q & 3;
    int n = row0 + nl;
    int ri = rel_idx[n * 3];
    int ei = ent_idx[n * 3];
    const float4* rg = reinterpret_cast<const float4*>(relg + (size_t)ri * 2048);
    const float4* eg = reinterpret_cast<const float4*>(entg + (size_t)ei * 2048);
    int b4 = uh * 16 + ul4;
    float4 gi = rg[b4],     gf = rg[b4 + 4],  gg = rg[b4 + 8],  go = rg[b4 + 12];
    float4 e0 = eg[b4],     e1 = eg[b4 + 4],  e2 = eg[b4 + 8],  e3 = eg[b4 + 12];
    gi.x += e0.x; gi.y += e0.y; gi.z += e0.z; gi.w += e0.w;
    gf.x += e1.x; gf.y += e1.y; gf.z += e1.z; gf.w += e1.w;
    gg.x += e2.x; gg.y += e2.y; gg.z += e2.z; gg.w += e2.w;
    go.x += e3.x; go.y += e3.y; go.z += e3.z; go.w += e3.w;
    float4 cn, hn;
    cn.x = sigf(gi.x) * tanhf(gg.x); hn.x = sigf(go.x) * tanhf(cn.x);
    cn.y = sigf(gi.y) * tanhf(gg.y); hn.y = sigf(go.y) * tanhf(cn.y);
    cn.z = sigf(gi.z) * tanhf(gg.z); hn.z = sigf(go.z) * tanhf(cn.z);
    cn.w = sigf(gi.w) * tanhf(gg.w); hn.w = sigf(go.w) * tanhf(cn.w);
    int u0 = uh * 16 + ul4 * 4;
    reinterpret_cast<float4*>(cbuf + (size_t)nl * 512)[u0 >> 2] = cn;
    ushort4 hu = make_ushort4(f2bf(hn.x), f2bf(hn.y), f2bf(hn.z), f2bf(hn.w));
    reinterpret_cast<ushort4*>(hbuf + (size_t)nl * 512)[u0 >> 2] = hu;
    int len = lens_[n];
    int last = len - 1;
    if (last < 0) last = 0;
    if (last > 2) last = 2;
    if (last == 0) {
        ushort4 pv = (len > 0) ? hu : make_ushort4(0, 0, 0, 0);
        reinterpret_cast<ushort4*>(pemb + (size_t)nl * 512)[u0 >> 2] = pv;
    }
}

// ---------------- per-pair attention -> mean-over-q context ----------------
__global__ __launch_bounds__(256) void attn_kernel(const float* __restrict__ qkv,
                                                   float* __restrict__ mctx, int pair0)
{
    __shared__ float qk[10][1024];
    __shared__ float sc[4][10][10];
    __shared__ float wb[4][10];
    int tid = threadIdx.x;
    const float* base = qkv + (size_t)blockIdx.x * 10 * 1536;
    for (int i = tid; i < 2560; i += 256) {
        int row = i >> 8, c4 = i & 255;
        reinterpret_cast<float4*>(&qk[row][0])[c4] =
            reinterpret_cast<const float4*>(base + (size_t)row * 1536)[c4];
    }
    __syncthreads();
    const float scale = 0.08838834764831845f; // 1/sqrt(128)
    for (int idx = tid; idx < 400; idx += 256) {
        int h = idx / 100, rem = idx % 100, qi = rem / 10, ki = rem % 10;
        const float* qp = &qk[qi][h * 128];
        const float* kp = &qk[ki][512 + h * 128];
        float a = 0.f;
        for (int d = 0; d < 128; ++d) a += qp[d] * kp[d];
        sc[h][qi][ki] = a * scale;
    }
    __syncthreads();
    if (tid < 40) {
        int h = tid / 10, qi = tid % 10;
        float m = -1e30f;
        for (int ki = 0; ki < 10; ++ki) m = fmaxf(m, sc[h][qi][ki]);
        float ex[10]; float s = 0.f;
        for (int ki = 0; ki < 10; ++ki) { ex[ki] = expf(sc[h][qi][ki] - m); s += ex[ki]; }
        float inv = 1.f / s;
        for (int ki = 0; ki < 10; ++ki) sc[h][qi][ki] = ex[ki] * inv;
    }
    __syncthreads();
    if (tid < 40) {
        int h = tid / 10, ki = tid % 10;
        float s = 0.f;
        for (int qi = 0; qi < 10; ++qi) s += sc[h][qi][ki];
        wb[h][ki] = s * 0.1f;
    }
    __syncthreads();
    for (int e = tid; e < 512; e += 256) {
        int h = e >> 7, d = e & 127;
        float a = 0.f;
        for (int ki = 0; ki < 10; ++ki)
            a += wb[h][ki] * base[(size_t)ki * 1536 + 1024 + h * 128 + d];
        mctx[(size_t)(pair0 + blockIdx.x) * 512 + e] = a;
    }
}

extern "C" void kernel_launch(void* const* d_in, const int* in_sizes, int n_in,
                              void* d_out, int out_size, void* d_ws, size_t ws_size,
                              hipStream_t stream)
{
    const int* rel_idx     = (const int*)d_in[0];
    const int* ent_idx     = (const int*)d_in[1];
    const int* path_lens   = (const int*)d_in[2];
    const float* rel_table = (const float*)d_in[3];
    const float* ent_table = (const float*)d_in[4];
    const float* kg_proj_w = (const float*)d_in[5];
    const float* kg_proj_b = (const float*)d_in[6];
    const float* w_ih      = (const float*)d_in[7];
    const float* w_hh      = (const float*)d_in[8];
    const float* b_ih      = (const float*)d_in[9];
    const float* b_hh      = (const float*)d_in[10];
    const float* attn_in_w = (const float*)d_in[11];
    const float* attn_in_b = (const float*)d_in[12];
    const float* attn_out_w = (const float*)d_in[13];
    const float* attn_out_b = (const float*)d_in[14];
    const float* path_proj_w = (const float*)d_in[15];
    const float* path_proj_b = (const float*)d_in[16];
    float* out = (float*)d_out;
    (void)in_sizes; (void)n_in; (void)out_size; (void)ws_size;

    float* ws = (float*)d_ws;
    size_t off = 0;
    auto alloc = [&](size_t n) { float* p = ws + off; off += (n + 63) & ~(size_t)63; return p; };
    auto allocu = [&](size_t n) { return (ushort*)alloc((n + 1) / 2); };
    int*   perm  = (int*)alloc(2048);
    float* kgT   = alloc((size_t)256 * 512);
    float* aoT   = alloc((size_t)512 * 512);
    float* CrelP = alloc((size_t)2048 * 256);
    float* CentP = alloc((size_t)2048 * 256);
    float* brelP = alloc(2048);
    float* bentP = alloc(2048);
    float* bcomb = alloc(512);
    float* Wcomb = alloc((size_t)512 * 512);
    float* relg  = alloc((size_t)REL_PAD * 2048);
    float* entg  = alloc((size_t)ENT_PAD * 2048);   // 82.8 MB
    float* mctx  = alloc((size_t)PP * 512);
    float* cch   = alloc((size_t)CH_ROWS * 512);
    float* big   = alloc((size_t)CH_ROWS * 1536);   // qkv scratch
    ushort* whhB  = allocu((size_t)2048 * 512);
    ushort* aiwB  = allocu((size_t)1536 * 512);
    ushort* hA    = allocu((size_t)CH_ROWS * 512);  // h ping
    ushort* hB    = allocu((size_t)CH_ROWS * 512);  // h pong
    ushort* pch   = allocu((size_t)CH_ROWS * 512);
    ushort* CrelBh = allocu((size_t)2048 * 256);
    ushort* CrelBl = allocu((size_t)2048 * 256);
    ushort* CentBh = allocu((size_t)2048 * 256);
    ushort* CentBl = allocu((size_t)2048 * 256);
    ushort* relBh  = allocu((size_t)REL_PAD * 256);
    ushort* relBl  = allocu((size_t)REL_PAD * 256);
    ushort* entBh  = allocu((size_t)ENT_PAD * 256);
    ushort* entBl  = allocu((size_t)ENT_PAD * 256);
    // total ≈ 144 MB

    auto gemm = [&](const float* A, int lda, const float* B, int ldb,
                    float* Cp, int ldc, int M, int N, int Kd, const float* bias,
                    const int* aperm) {
        dim3 g((unsigned)((N + 63) / 64), (unsigned)((M + 127) / 128));
        gemm_abt<<<g, 256, 0, stream>>>(A, lda, B, ldb, Cp, ldc, M, N, Kd, bias, aperm);
    };

    // ---- prologue: permutation + combined weights ----
    make_perm<<<8, 256, 0, stream>>>(perm);
    transpose_k<<<dim3(256 / 32, 512 / 32), 256, 0, stream>>>(kg_proj_w, kgT, 512, 256);
    transpose_k<<<dim3(512 / 32, 512 / 32), 256, 0, stream>>>(attn_out_w, aoT, 512, 512);
    // CrelP = W_ih[perm, :H] @ kg_proj ; CentP = W_ih[perm, H:] @ kg_proj
    gemm(w_ih,       1024, kgT, 512, CrelP, 256, 2048, 256, 512, nullptr, perm);
    gemm(w_ih + 512, 1024, kgT, 512, CentP, 256, 2048, 256, 512, nullptr, perm);
    rowdot<<<2048 / 4, 256, 0, stream>>>(w_ih,       1024, kg_proj_b, 512, b_ih, b_hh, brelP, 2048, perm);
    rowdot<<<2048 / 4, 256, 0, stream>>>(w_ih + 512, 1024, kg_proj_b, 512, nullptr, nullptr, bentP, 2048, perm);
    rowdot<<<512 / 4, 256, 0, stream>>>(path_proj_w, 512, attn_out_b, 512, path_proj_b, nullptr, bcomb, 512, nullptr);
    gemm(path_proj_w, 512, aoT, 512, Wcomb, 512, 512, 512, 512, nullptr, nullptr);

    // ---- bf16 conversions / splits ----
    f2bf_perm_rows<<<(2048 * 128 + 255) / 256, 256, 0, stream>>>(w_hh, whhB, perm, 2048, 128);
    f2bf_k<<<(1536 * 128 + 255) / 256, 256, 0, stream>>>(attn_in_w, aiwB, 1536 * 128);
    f2bf_split<<<(2048 * 64 + 255) / 256, 256, 0, stream>>>(CrelP, CrelBh, CrelBl, 2048 * 64, 2048 * 64);
    f2bf_split<<<(2048 * 64 + 255) / 256, 256, 0, stream>>>(CentP, CentBh, CentBl, 2048 * 64, 2048 * 64);
    f2bf_split<<<(REL_PAD * 64 + 255) / 256, 256, 0, stream>>>(rel_table, relBh, relBl, 200 * 64, REL_PAD * 64);
    f2bf_split<<<(ENT_PAD * 64 + 255) / 256, 256, 0, stream>>>(ent_table, entBh, entBl, 10000 * 64, ENT_PAD * 64);

    // ---- gate tables via split-bf16 MFMA (fp32-level accuracy) ----
    gemm_bf16s<<<dim3(2048 / 128, REL_PAD / 128), 256, 0, stream>>>(
        relBh, relBl, CrelBh, CrelBl, relg, REL_PAD, 2048, 256, 2048, brelP);
    gemm_bf16s<<<dim3(2048 / 128, ENT_PAD / 128), 256, 0, stream>>>(
        entBh, entBl, CentBh, CentBl, entg, ENT_PAD, 2048, 256, 2048, bentP);

    // ---- chunked pipeline: t0 -> fused gemm_lstm x2 (h ping-pong) -> qkv -> attn ----
    for (int ch = 0; ch < N_CHUNK; ++ch) {
        int row0 = ch * CH_ROWS;
        int pair0 = ch * CH_PAIRS;
        lstm_t0<<<(CH_ROWS * 128) / 256, 256, 0, stream>>>(
            relg, entg, rel_idx, ent_idx, path_lens, hA, cch, pch, row0, CH_ROWS);
        gemm_lstm<<<dim3(16, 20), 256, 0, stream>>>(
            hA, whhB, relg, entg, rel_idx, ent_idx, path_lens,
            hB, cch, pch, 1, row0);
        gemm_lstm<<<dim3(16, 20), 256, 0, stream>>>(
            hB, whhB, relg, entg, rel_idx, ent_idx, path_lens,
            hA, cch, pch, 2, row0);
        gemm_bf16<<<dim3(1536 / 128, CH_ROWS / 128), 256, 0, stream>>>(
            pch, aiwB, big, CH_ROWS, 1536, 512, 1536, attn_in_b);
        attn_kernel<<<CH_PAIRS, 256, 0, stream>>>(big, mctx, pair0);
    }

    // ---- out = mctx @ Wcomb^T + bcomb (fp32) ----
    gemm(mctx, 512, Wcomb, 512, out, 512, PP, 512, 512, bcomb, nullptr);
}

// Round 6
// 745.231 us; speedup vs baseline: 3.9956x; 1.6037x over previous
//
#include <hip/hip_runtime.h>
#include <cstdint>
#include <cstddef>

#define PP 2048
#define KK 10
#define HH 512
#define NPK (PP*KK)       // 20480
#define ENT_PAD 10112     // 79*128
#define REL_PAD 256
#define HALF_PAIRS 1024
#define HALF_ROWS (HALF_PAIRS*KK)  // 10240

using f32x4  = __attribute__((ext_vector_type(4))) float;
using short8 = __attribute__((ext_vector_type(8))) short;

__device__ __forceinline__ float sigf(float x) { return 1.0f / (1.0f + expf(-x)); }

__device__ __forceinline__ ushort f2bf(float x) {
    union { float f; uint32_t u; } v; v.f = x;
    uint32_t r = v.u + 0x7FFF + ((v.u >> 16) & 1);
    return (ushort)(r >> 16);
}
__device__ __forceinline__ float bf2f(ushort u) {
    union { uint32_t u; float f; } v; v.u = ((uint32_t)u) << 16;
    return v.f;
}

// perm[p] = old gate row for permuted row p; bihh[p] = b_ih[old]+b_hh[old]
// p = uh*64 + g*16 + ul (unit u = uh*16+ul), old = g*512 + u
__global__ __launch_bounds__(256) void perm_bias(int* __restrict__ perm,
                                                 float* __restrict__ bihh,
                                                 const float* __restrict__ b_ih,
                                                 const float* __restrict__ b_hh) {
    int p = blockIdx.x * 256 + threadIdx.x;
    if (p < 2048) {
        int uh = p >> 6, g = (p >> 4) & 3, ul = p & 15;
        int old = g * 512 + uh * 16 + ul;
        perm[p] = old;
        bihh[p] = b_ih[old] + b_hh[old];
    }
}

// ---------------- tiled transpose: dst[C][R] = src[R][C] ----------------
__global__ __launch_bounds__(256) void transpose_k(const float* __restrict__ src,
                                                   float* __restrict__ dst, int R, int C) {
    __shared__ float t[32][33];
    int bx = blockIdx.x * 32, by = blockIdx.y * 32;
    int x = threadIdx.x & 31, y = threadIdx.x >> 5;
    for (int i = y; i < 32; i += 8) {
        int r = by + i, c = bx + x;
        if (r < R && c < C) t[i][x] = src[(size_t)r * C + c];
    }
    __syncthreads();
    for (int i = y; i < 32; i += 8) {
        int c = bx + i, r = by + x;
        if (r < R && c < C) dst[(size_t)c * R + r] = t[x][i];
    }
}

// ------------- out[j] = dot(A[j,:Kd], vec) + add1[j] -------------
__global__ __launch_bounds__(256) void rowdot(const float* __restrict__ A, int lda,
                                              const float* __restrict__ vec, int Kd,
                                              const float* __restrict__ add1,
                                              float* __restrict__ out, int M) {
    int w = threadIdx.x >> 6, lane = threadIdx.x & 63;
    int row = blockIdx.x * 4 + w;
    if (row >= M) return;
    float acc = 0.f;
    for (int k = lane; k < Kd; k += 64) acc += A[(size_t)row * lda + k] * vec[k];
    for (int off = 32; off; off >>= 1) acc += __shfl_down(acc, off, 64);
    if (lane == 0) {
        float r = acc;
        if (add1) r += add1[row];
        out[row] = r;
    }
}

// ---- 2D strided fp32 -> (hi,lo) bf16 split, optional row perm, zero row padding ----
__global__ __launch_bounds__(256) void f2bf_split2d(const float* __restrict__ src,
                                                    int lda, int col0,
                                                    ushort* __restrict__ hi,
                                                    ushort* __restrict__ lo,
                                                    int nsrc_rows, int ncols, int ndst_rows,
                                                    const int* __restrict__ perm) {
    int i = blockIdx.x * 256 + threadIdx.x;
    int nc4 = ncols >> 2;
    if (i >= ndst_rows * nc4) return;
    int row = i / nc4, c4 = i % nc4;
    ushort4 h = make_ushort4(0, 0, 0, 0), l = make_ushort4(0, 0, 0, 0);
    if (row < nsrc_rows) {
        int sr = perm ? perm[row] : row;
        float4 v = *reinterpret_cast<const float4*>(src + (size_t)sr * lda + col0 + c4 * 4);
        h = make_ushort4(f2bf(v.x), f2bf(v.y), f2bf(v.z), f2bf(v.w));
        l = make_ushort4(f2bf(v.x - bf2f(h.x)), f2bf(v.y - bf2f(h.y)),
                         f2bf(v.z - bf2f(h.z)), f2bf(v.w - bf2f(h.w)));
    }
    reinterpret_cast<ushort4*>(hi)[i] = h;
    reinterpret_cast<ushort4*>(lo)[i] = l;
}

// ---- fp32 -> bf16 bulk (n4 float4 groups) ----
__global__ __launch_bounds__(256) void f2bf_k(const float* __restrict__ s,
                                              ushort* __restrict__ d, int n4) {
    int i = blockIdx.x * 256 + threadIdx.x;
    if (i < n4) {
        float4 v = reinterpret_cast<const float4*>(s)[i];
        reinterpret_cast<ushort4*>(d)[i] = make_ushort4(f2bf(v.x), f2bf(v.y), f2bf(v.z), f2bf(v.w));
    }
}

// ---- permuted-row fp32 -> bf16 (w_hh -> whhB) ----
__global__ __launch_bounds__(256) void f2bf_perm_rows(const float* __restrict__ s,
                                                      ushort* __restrict__ d,
                                                      const int* __restrict__ perm,
                                                      int nrows, int ncols4) {
    int i = blockIdx.x * 256 + threadIdx.x;
    if (i >= nrows * ncols4) return;
    int row = i / ncols4, c4 = i % ncols4;
    int sr = perm[row];
    float4 v = reinterpret_cast<const float4*>(s + (size_t)sr * ncols4 * 4)[c4];
    reinterpret_cast<ushort4*>(d + (size_t)row * ncols4 * 4)[c4] =
        make_ushort4(f2bf(v.x), f2bf(v.y), f2bf(v.z), f2bf(v.w));
}

// ---------------- bf16 MFMA GEMM: C[M,N](f32) = A@B^T (+bias). M,N%128==0, K%64==0 ----
__global__ __launch_bounds__(256) void gemm_bf16(
    const ushort* __restrict__ A, const ushort* __restrict__ B,
    float* __restrict__ C, int M, int N, int K, int ldc,
    const float* __restrict__ bias)
{
    __shared__ ushort As[128 * 64];
    __shared__ ushort Bs[128 * 64];
    int tid = threadIdx.x;
    int lane = tid & 63;
    int w = tid >> 6;
    int wr = w >> 1, wc = w & 1;
    int col0 = blockIdx.x * 128, row0 = blockIdx.y * 128;

    f32x4 acc[4][4];
#pragma unroll
    for (int m = 0; m < 4; ++m)
#pragma unroll
        for (int n = 0; n < 4; ++n) acc[m][n] = {0.f, 0.f, 0.f, 0.f};

    int rA = lane & 15;
    int kq = lane >> 4;

    for (int kt = 0; kt < K; kt += 64) {
#pragma unroll
        for (int it = 0; it < 4; ++it) {
            int c = it * 256 + tid;
            int row = c >> 3, ch = c & 7;
            int cs = ch ^ (row & 7);
            uint4 va = *reinterpret_cast<const uint4*>(A + (size_t)(row0 + row) * K + kt + ch * 8);
            *reinterpret_cast<uint4*>(&As[(size_t)row * 64 + cs * 8]) = va;
            uint4 vb = *reinterpret_cast<const uint4*>(B + (size_t)(col0 + row) * K + kt + ch * 8);
            *reinterpret_cast<uint4*>(&Bs[(size_t)row * 64 + cs * 8]) = vb;
        }
        __syncthreads();
#pragma unroll
        for (int s = 0; s < 2; ++s) {
            int csw = (s * 4 + kq) ^ (rA & 7);
            short8 af[4], bfr[4];
#pragma unroll
            for (int m = 0; m < 4; ++m) {
                int rowA = wr * 64 + m * 16 + rA;
                af[m] = *reinterpret_cast<const short8*>(&As[(size_t)rowA * 64 + csw * 8]);
            }
#pragma unroll
            for (int n = 0; n < 4; ++n) {
                int rowB = wc * 64 + n * 16 + rA;
                bfr[n] = *reinterpret_cast<const short8*>(&Bs[(size_t)rowB * 64 + csw * 8]);
            }
#pragma unroll
            for (int m = 0; m < 4; ++m)
#pragma unroll
                for (int n = 0; n < 4; ++n)
                    acc[m][n] = __builtin_amdgcn_mfma_f32_16x16x32_bf16(af[m], bfr[n], acc[m][n], 0, 0, 0);
        }
        __syncthreads();
    }
#pragma unroll
    for (int n = 0; n < 4; ++n) {
        int gcol = col0 + wc * 64 + n * 16 + rA;
        float bv = bias ? bias[gcol] : 0.f;
#pragma unroll
        for (int m = 0; m < 4; ++m) {
            int grow0 = row0 + wr * 64 + m * 16 + kq * 4;
#pragma unroll
            for (int r = 0; r < 4; ++r)
                C[(size_t)(grow0 + r) * ldc + gcol] = acc[m][n][r] + bv;
        }
    }
}

// ------------- split-bf16 GEMM (fp32-accuracy): C = Ah.Bh^T + Ah.Bl^T + Al.Bh^T + bias
__global__ __launch_bounds__(256) void gemm_bf16s(
    const ushort* __restrict__ Ah, const ushort* __restrict__ Al,
    const ushort* __restrict__ Bh, const ushort* __restrict__ Bl,
    float* __restrict__ C, int M, int N, int K, int ldc,
    const float* __restrict__ bias)
{
    __shared__ ushort Ash[128 * 64];
    __shared__ ushort Asl[128 * 64];
    __shared__ ushort Bsh[128 * 64];
    __shared__ ushort Bsl[128 * 64];
    int tid = threadIdx.x;
    int lane = tid & 63;
    int w = tid >> 6;
    int wr = w >> 1, wc = w & 1;
    int col0 = blockIdx.x * 128, row0 = blockIdx.y * 128;

    f32x4 acc[4][4];
#pragma unroll
    for (int m = 0; m < 4; ++m)
#pragma unroll
        for (int n = 0; n < 4; ++n) acc[m][n] = {0.f, 0.f, 0.f, 0.f};

    int rA = lane & 15;
    int kq = lane >> 4;

    for (int kt = 0; kt < K; kt += 64) {
#pragma unroll
        for (int it = 0; it < 4; ++it) {
            int c = it * 256 + tid;
            int row = c >> 3, ch = c & 7;
            int cs = ch ^ (row & 7);
            size_t ga = (size_t)(row0 + row) * K + kt + ch * 8;
            size_t gb = (size_t)(col0 + row) * K + kt + ch * 8;
            size_t la = (size_t)row * 64 + cs * 8;
            *reinterpret_cast<uint4*>(&Ash[la]) = *reinterpret_cast<const uint4*>(Ah + ga);
            *reinterpret_cast<uint4*>(&Asl[la]) = *reinterpret_cast<const uint4*>(Al + ga);
            *reinterpret_cast<uint4*>(&Bsh[la]) = *reinterpret_cast<const uint4*>(Bh + gb);
            *reinterpret_cast<uint4*>(&Bsl[la]) = *reinterpret_cast<const uint4*>(Bl + gb);
        }
        __syncthreads();
#pragma unroll
        for (int s = 0; s < 2; ++s) {
            int csw = (s * 4 + kq) ^ (rA & 7);
            short8 xh[4], yh[4], t4[4];
#pragma unroll
            for (int m = 0; m < 4; ++m) {
                int rowA = wr * 64 + m * 16 + rA;
                xh[m] = *reinterpret_cast<const short8*>(&Ash[(size_t)rowA * 64 + csw * 8]);
            }
#pragma unroll
            for (int n = 0; n < 4; ++n) {
                int rowB = wc * 64 + n * 16 + rA;
                yh[n] = *reinterpret_cast<const short8*>(&Bsh[(size_t)rowB * 64 + csw * 8]);
            }
#pragma unroll
            for (int m = 0; m < 4; ++m)
#pragma unroll
                for (int n = 0; n < 4; ++n)
                    acc[m][n] = __builtin_amdgcn_mfma_f32_16x16x32_bf16(xh[m], yh[n], acc[m][n], 0, 0, 0);
#pragma unroll
            for (int n = 0; n < 4; ++n) {
                int rowB = wc * 64 + n * 16 + rA;
                t4[n] = *reinterpret_cast<const short8*>(&Bsl[(size_t)rowB * 64 + csw * 8]);
            }
#pragma unroll
            for (int m = 0; m < 4; ++m)
#pragma unroll
                for (int n = 0; n < 4; ++n)
                    acc[m][n] = __builtin_amdgcn_mfma_f32_16x16x32_bf16(xh[m], t4[n], acc[m][n], 0, 0, 0);
#pragma unroll
            for (int m = 0; m < 4; ++m) {
                int rowA = wr * 64 + m * 16 + rA;
                t4[m] = *reinterpret_cast<const short8*>(&Asl[(size_t)rowA * 64 + csw * 8]);
            }
#pragma unroll
            for (int m = 0; m < 4; ++m)
#pragma unroll
                for (int n = 0; n < 4; ++n)
                    acc[m][n] = __builtin_amdgcn_mfma_f32_16x16x32_bf16(t4[m], yh[n], acc[m][n], 0, 0, 0);
        }
        __syncthreads();
    }
#pragma unroll
    for (int n = 0; n < 4; ++n) {
        int gcol = col0 + wc * 64 + n * 16 + rA;
        float bv = bias ? bias[gcol] : 0.f;
#pragma unroll
        for (int m = 0; m < 4; ++m) {
            int grow0 = row0 + wr * 64 + m * 16 + kq * 4;
#pragma unroll
            for (int r = 0; r < 4; ++r)
                C[(size_t)(grow0 + r) * ldc + gcol] = acc[m][n][r] + bv;
        }
    }
}

// ---------------- FUSED: G = h_in@whhB^T, LSTM pointwise epilogue. Full-size. -------
// M=NPK(20480), N=2048(perm gate layout), K=512. grid (16, 160).
// h ping-pong: A (h at t-1) and hbuf (h at t) MUST differ (cross-block read/write race).
__global__ __launch_bounds__(256) void gemm_lstm(
    const ushort* __restrict__ A, const ushort* __restrict__ B,
    const float* __restrict__ relg, const float* __restrict__ entg,
    const int* __restrict__ rel_idx, const int* __restrict__ ent_idx,
    const int* __restrict__ lens_,
    ushort* __restrict__ hbuf, float* __restrict__ cbuf, ushort* __restrict__ pemb,
    int t)
{
    __shared__ ushort As[128 * 64];
    __shared__ ushort Bs[128 * 64];
    const int K = 512;
    int tid = threadIdx.x;
    int lane = tid & 63;
    int w = tid >> 6;
    int wr = w >> 1, wc = w & 1;
    int col0 = blockIdx.x * 128, row0 = blockIdx.y * 128;

    f32x4 acc[4][4];
#pragma unroll
    for (int m = 0; m < 4; ++m)
#pragma unroll
        for (int n = 0; n < 4; ++n) acc[m][n] = {0.f, 0.f, 0.f, 0.f};

    int rA = lane & 15;
    int kq = lane >> 4;

    for (int kt = 0; kt < K; kt += 64) {
#pragma unroll
        for (int it = 0; it < 4; ++it) {
            int c = it * 256 + tid;
            int row = c >> 3, ch = c & 7;
            int cs = ch ^ (row & 7);
            uint4 va = *reinterpret_cast<const uint4*>(A + (size_t)(row0 + row) * K + kt + ch * 8);
            *reinterpret_cast<uint4*>(&As[(size_t)row * 64 + cs * 8]) = va;
            uint4 vb = *reinterpret_cast<const uint4*>(B + (size_t)(col0 + row) * K + kt + ch * 8);
            *reinterpret_cast<uint4*>(&Bs[(size_t)row * 64 + cs * 8]) = vb;
        }
        __syncthreads();
#pragma unroll
        for (int s = 0; s < 2; ++s) {
            int csw = (s * 4 + kq) ^ (rA & 7);
            short8 af[4], bfr[4];
#pragma unroll
            for (int m = 0; m < 4; ++m) {
                int rowA = wr * 64 + m * 16 + rA;
                af[m] = *reinterpret_cast<const short8*>(&As[(size_t)rowA * 64 + csw * 8]);
            }
#pragma unroll
            for (int n = 0; n < 4; ++n) {
                int rowB = wc * 64 + n * 16 + rA;
                bfr[n] = *reinterpret_cast<const short8*>(&Bs[(size_t)rowB * 64 + csw * 8]);
            }
#pragma unroll
            for (int m = 0; m < 4; ++m)
#pragma unroll
                for (int n = 0; n < 4; ++n)
                    acc[m][n] = __builtin_amdgcn_mfma_f32_16x16x32_bf16(af[m], bfr[n], acc[m][n], 0, 0, 0);
        }
        __syncthreads();
    }

    // fused LSTM epilogue: this lane owns unit u = uh*16+rA, uh = bx*2+wc
    int uh = blockIdx.x * 2 + wc;
    int u  = uh * 16 + rA;
    int colbase = uh * 64 + rA;
#pragma unroll
    for (int m = 0; m < 4; ++m) {
#pragma unroll
        for (int r = 0; r < 4; ++r) {
            int n = row0 + wr * 64 + m * 16 + kq * 4 + r;   // global path row
            int ri = rel_idx[n * 3 + t];
            int ei = ent_idx[n * 3 + t];
            const float* rr = relg + (size_t)ri * 2048 + colbase;
            const float* er = entg + (size_t)ei * 2048 + colbase;
            float gi = acc[m][0][r] + rr[0]  + er[0];
            float gf = acc[m][1][r] + rr[16] + er[16];
            float gg = acc[m][2][r] + rr[32] + er[32];
            float go = acc[m][3][r] + rr[48] + er[48];
            float cold = cbuf[(size_t)n * 512 + u];
            float cn = sigf(gf) * cold + sigf(gi) * tanhf(gg);
            float hn = sigf(go) * tanhf(cn);
            cbuf[(size_t)n * 512 + u] = cn;
            ushort hu = f2bf(hn);
            hbuf[(size_t)n * 512 + u] = hu;
            int len = lens_[n];
            int last = len - 1;
            if (last < 0) last = 0;
            if (last > 2) last = 2;
            if (last == t) pemb[(size_t)n * 512 + u] = (len > 0) ? hu : (ushort)0;
        }
    }
}

// ---------------- LSTM t=0 (no recurrent term), permuted gate tables ----------------
__global__ __launch_bounds__(256) void lstm_t0(
    const float* __restrict__ relg, const float* __restrict__ entg,
    const int* __restrict__ rel_idx, const int* __restrict__ ent_idx,
    const int* __restrict__ lens_,
    ushort* __restrict__ hbuf, float* __restrict__ cbuf, ushort* __restrict__ pemb,
    int nrows)
{
    int gid = blockIdx.x * 256 + threadIdx.x;
    if (gid >= nrows * 128) return;
    int nl = gid >> 7, q = gid & 127;
    int uh = q >> 2, ul4 = q & 3;
    int ri = rel_idx[nl * 3];
    int ei = ent_idx[nl * 3];
    const float4* rg = reinterpret_cast<const float4*>(relg + (size_t)ri * 2048);
    const float4* eg = reinterpret_cast<const float4*>(entg + (size_t)ei * 2048);
    int b4 = uh * 16 + ul4;
    float4 gi = rg[b4], gf = rg[b4 + 4], gg = rg[b4 + 8], go = rg[b4 + 12];
    float4 e0 = eg[b4], e1 = eg[b4 + 4], e2 = eg[b4 + 8], e3 = eg[b4 + 12];
    gi.x += e0.x; gi.y += e0.y; gi.z += e0.z; gi.w += e0.w;
    gf.x += e1.x; gf.y += e1.y; gf.z += e1.z; gf.w += e1.w;
    gg.x += e2.x; gg.y += e2.y; gg.z += e2.z; gg.w += e2.w;
    go.x += e3.x; go.y += e3.y; go.z += e3.z; go.w += e3.w;
    (void)gf;
    float4 cn, hn;
    cn.x = sigf(gi.x) * tanhf(gg.x); hn.x = sigf(go.x) * tanhf(cn.x);
    cn.y = sigf(gi.y) * tanhf(gg.y); hn.y = sigf(go.y) * tanhf(cn.y);
    cn.z = sigf(gi.z) * tanhf(gg.z); hn.z = sigf(go.z) * tanhf(cn.z);
    cn.w = sigf(gi.w) * tanhf(gg.w); hn.w = sigf(go.w) * tanhf(cn.w);
    int u4 = uh * 4 + ul4;   // float4 index within 512-wide row
    reinterpret_cast<float4*>(cbuf + (size_t)nl * 512)[u4] = cn;
    ushort4 hu = make_ushort4(f2bf(hn.x), f2bf(hn.y), f2bf(hn.z), f2bf(hn.w));
    reinterpret_cast<ushort4*>(hbuf + (size_t)nl * 512)[u4] = hu;
    int len = lens_[nl];
    int last = len - 1;
    if (last < 0) last = 0;
    if (last > 2) last = 2;
    if (last == 0) {
        ushort4 pv = (len > 0) ? hu : make_ushort4(0, 0, 0, 0);
        reinterpret_cast<ushort4*>(pemb + (size_t)nl * 512)[u4] = pv;
    }
}

// ---------------- per-pair attention -> mean-over-q context ----------------
__global__ __launch_bounds__(256) void attn_kernel(const float* __restrict__ qkv,
                                                   float* __restrict__ mctx, int pair0)
{
    __shared__ float qk[10][1024];
    __shared__ float sc[4][10][10];
    __shared__ float wb[4][10];
    int tid = threadIdx.x;
    const float* base = qkv + (size_t)blockIdx.x * 10 * 1536;
    for (int i = tid; i < 2560; i += 256) {
        int row = i >> 8, c4 = i & 255;
        reinterpret_cast<float4*>(&qk[row][0])[c4] =
            reinterpret_cast<const float4*>(base + (size_t)row * 1536)[c4];
    }
    __syncthreads();
    const float scale = 0.08838834764831845f; // 1/sqrt(128)
    for (int idx = tid; idx < 400; idx += 256) {
        int h = idx / 100, rem = idx % 100, qi = rem / 10, ki = rem % 10;
        const float* qp = &qk[qi][h * 128];
        const float* kp = &qk[ki][512 + h * 128];
        float a = 0.f;
        for (int d = 0; d < 128; ++d) a += qp[d] * kp[d];
        sc[h][qi][ki] = a * scale;
    }
    __syncthreads();
    if (tid < 40) {
        int h = tid / 10, qi = tid % 10;
        float m = -1e30f;
        for (int ki = 0; ki < 10; ++ki) m = fmaxf(m, sc[h][qi][ki]);
        float ex[10]; float s = 0.f;
        for (int ki = 0; ki < 10; ++ki) { ex[ki] = expf(sc[h][qi][ki] - m); s += ex[ki]; }
        float inv = 1.f / s;
        for (int ki = 0; ki < 10; ++ki) sc[h][qi][ki] = ex[ki] * inv;
    }
    __syncthreads();
    if (tid < 40) {
        int h = tid / 10, ki = tid % 10;
        float s = 0.f;
        for (int qi = 0; qi < 10; ++qi) s += sc[h][qi][ki];
        wb[h][ki] = s * 0.1f;
    }
    __syncthreads();
    for (int e = tid; e < 512; e += 256) {
        int h = e >> 7, d = e & 127;
        float a = 0.f;
        for (int ki = 0; ki < 10; ++ki)
            a += wb[h][ki] * base[(size_t)ki * 1536 + 1024 + h * 128 + d];
        mctx[(size_t)(pair0 + blockIdx.x) * 512 + e] = a;
    }
}

extern "C" void kernel_launch(void* const* d_in, const int* in_sizes, int n_in,
                              void* d_out, int out_size, void* d_ws, size_t ws_size,
                              hipStream_t stream)
{
    const int* rel_idx     = (const int*)d_in[0];
    const int* ent_idx     = (const int*)d_in[1];
    const int* path_lens   = (const int*)d_in[2];
    const float* rel_table = (const float*)d_in[3];
    const float* ent_table = (const float*)d_in[4];
    const float* kg_proj_w = (const float*)d_in[5];
    const float* kg_proj_b = (const float*)d_in[6];
    const float* w_ih      = (const float*)d_in[7];
    const float* w_hh      = (const float*)d_in[8];
    const float* b_ih      = (const float*)d_in[9];
    const float* b_hh      = (const float*)d_in[10];
    const float* attn_in_w = (const float*)d_in[11];
    const float* attn_in_b = (const float*)d_in[12];
    const float* attn_out_w = (const float*)d_in[13];
    const float* attn_out_b = (const float*)d_in[14];
    const float* path_proj_w = (const float*)d_in[15];
    const float* path_proj_b = (const float*)d_in[16];
    float* out = (float*)d_out;
    (void)in_sizes; (void)n_in; (void)out_size; (void)ws_size;

    float* ws = (float*)d_ws;
    size_t off = 0;
    auto alloc = [&](size_t n) { float* p = ws + off; off += (n + 63) & ~(size_t)63; return p; };
    // ---- persistent (float units) ----
    int*    perm  = (int*)alloc(2048);
    float*  bihh  = alloc(2048);
    float*  bcomb = alloc(512);
    float*  relg  = alloc((size_t)REL_PAD * 2048);       // 2 MB
    float*  entg  = alloc((size_t)ENT_PAD * 2048);       // 82.8 MB
    float*  mctx  = alloc((size_t)PP * 512);             // 4 MB
    ushort* whhB  = (ushort*)alloc((size_t)2048 * 256);  // 2048x512 bf16
    ushort* aiwB  = (ushort*)alloc((size_t)1536 * 256);  // 1536x512 bf16
    ushort* pch   = (ushort*)alloc((size_t)NPK * 256);   // pemb bf16, 21 MB
    ushort* Wch   = (ushort*)alloc((size_t)512 * 256);   // Wcomb hi
    ushort* Wcl   = (ushort*)alloc((size_t)512 * 256);   // Wcomb lo
    // ---- phase-shared region (80 MB) ----
    float* R = alloc((size_t)21000000);

    // phase P offsets (prologue split/temps) — dead before LSTM starts
    size_t ro = 0;
    auto ral = [&](size_t n) { float* p = R + ro; ro += n; return p; };
    ushort* kgWh  = (ushort*)ral(65536);   ushort* kgWl  = (ushort*)ral(65536);
    ushort* relBh = (ushort*)ral(32768);   ushort* relBl = (ushort*)ral(32768);
    ushort* entBh = (ushort*)ral(1294336); ushort* entBl = (ushort*)ral(1294336);
    ushort* wrelh = (ushort*)ral(524288);  ushort* wrell = (ushort*)ral(524288);
    ushort* wenth = (ushort*)ral(524288);  ushort* wentl = (ushort*)ral(524288);
    float*  rel_pf = ral(131072);
    float*  ent_pf = ral(5177344);
    ushort* rel_ph = (ushort*)ral(65536);   ushort* rel_pl = (ushort*)ral(65536);
    ushort* ent_ph = (ushort*)ral(2588672); ushort* ent_pl = (ushort*)ral(2588672);
    float*  aoT    = ral(262144);
    ushort* pph  = (ushort*)ral(131072); ushort* ppl  = (ushort*)ral(131072);
    ushort* aoTh = (ushort*)ral(131072); ushort* aoTl = (ushort*)ral(131072);
    float*  WcombF = ral(262144);
    // phase L (LSTM): fp32 c + h ping-pong — overlays phase P
    float*  cb = R;                               // 20480*512 fp32 = 10.49M fl
    ushort* hA = (ushort*)(R + 10485760);         // 20480*512 bf16
    ushort* hB = (ushort*)(R + 15728640);         // 20480*512 bf16 (end 20.97M fl)
    // phase A (attn): qkv half = 10240*1536 fp32 = 15.73M fl — overlays phase L
    float*  qkv = R;
    // phase F: mctx splits
    ushort* mch = (ushort*)R;
    ushort* mcl = (ushort*)(R + 524288);

    auto split = [&](const float* src, int lda, int col0, ushort* hi, ushort* lo,
                     int nsrc, int ncols, int ndst, const int* pm) {
        int total = ndst * (ncols / 4);
        f2bf_split2d<<<(total + 255) / 256, 256, 0, stream>>>(src, lda, col0, hi, lo, nsrc, ncols, ndst, pm);
    };
    auto gemms = [&](const ushort* Ah, const ushort* Al, const ushort* Bh, const ushort* Bl,
                     float* Cp, int M, int N, int Kd, int ldc, const float* bias) {
        gemm_bf16s<<<dim3((unsigned)(N / 128), (unsigned)(M / 128)), 256, 0, stream>>>(
            Ah, Al, Bh, Bl, Cp, M, N, Kd, ldc, bias);
    };

    // ======== prologue ========
    perm_bias<<<8, 256, 0, stream>>>(perm, bihh, b_ih, b_hh);
    transpose_k<<<dim3(16, 16), 256, 0, stream>>>(attn_out_w, aoT, 512, 512);
    split(kg_proj_w, 256, 0, kgWh, kgWl, 512, 256, 512, nullptr);
    split(rel_table, 256, 0, relBh, relBl, 200, 256, REL_PAD, nullptr);
    split(ent_table, 256, 0, entBh, entBl, 10000, 256, ENT_PAD, nullptr);
    split(w_ih, 1024, 0,   wrelh, wrell, 2048, 512, 2048, perm);
    split(w_ih, 1024, 512, wenth, wentl, 2048, 512, 2048, perm);
    split(path_proj_w, 512, 0, pph, ppl, 512, 512, 512, nullptr);
    split(aoT, 512, 0, aoTh, aoTl, 512, 512, 512, nullptr);
    f2bf_perm_rows<<<1024, 256, 0, stream>>>(w_hh, whhB, perm, 2048, 128);
    f2bf_k<<<768, 256, 0, stream>>>(attn_in_w, aiwB, 1536 * 128);
    rowdot<<<128, 256, 0, stream>>>(path_proj_w, 512, attn_out_b, 512, path_proj_b, bcomb, 512);

    // projected tables: rel_p = relT@kgW^T + b ; ent_p likewise (split-bf16, fp32-level)
    gemms(relBh, relBl, kgWh, kgWl, rel_pf, REL_PAD, 512, 256, 512, kg_proj_b);
    gemms(entBh, entBl, kgWh, kgWl, ent_pf, ENT_PAD, 512, 256, 512, kg_proj_b);
    split(rel_pf, 512, 0, rel_ph, rel_pl, REL_PAD, 512, REL_PAD, nullptr);
    split(ent_pf, 512, 0, ent_ph, ent_pl, ENT_PAD, 512, ENT_PAD, nullptr);
    // gate tables: relg = rel_p@Wrel^T + (b_ih+b_hh) ; entg = ent_p@Went^T
    gemms(rel_ph, rel_pl, wrelh, wrell, relg, REL_PAD, 2048, 512, 2048, bihh);
    gemms(ent_ph, ent_pl, wenth, wentl, entg, ENT_PAD, 2048, 512, 2048, nullptr);
    // Wcomb = path_proj_w @ attn_out_w  (then split for the final GEMM)
    gemms(pph, ppl, aoTh, aoTl, WcombF, 512, 512, 512, 512, nullptr);
    split(WcombF, 512, 0, Wch, Wcl, 512, 512, 512, nullptr);

    // ======== LSTM, full-size ========
    lstm_t0<<<(NPK * 128) / 256, 256, 0, stream>>>(
        relg, entg, rel_idx, ent_idx, path_lens, hA, cb, pch, NPK);
    gemm_lstm<<<dim3(16, 160), 256, 0, stream>>>(
        hA, whhB, relg, entg, rel_idx, ent_idx, path_lens, hB, cb, pch, 1);
    gemm_lstm<<<dim3(16, 160), 256, 0, stream>>>(
        hB, whhB, relg, entg, rel_idx, ent_idx, path_lens, hA, cb, pch, 2);

    // ======== qkv + attention, 2 halves ========
    for (int h = 0; h < 2; ++h) {
        gemm_bf16<<<dim3(12, 80), 256, 0, stream>>>(
            pch + (size_t)h * HALF_ROWS * 512, aiwB, qkv, HALF_ROWS, 1536, 512, 1536, attn_in_b);
        attn_kernel<<<HALF_PAIRS, 256, 0, stream>>>(qkv, mctx, h * HALF_PAIRS);
    }

    // ======== out = mctx @ Wcomb^T + bcomb (split-bf16) ========
    split(mctx, 512, 0, mch, mcl, 2048, 512, 2048, nullptr);
    gemms(mch, mcl, Wch, Wcl, out, 2048, 512, 512, 512, bcomb);
}